// Round 4
// baseline (453.761 us; speedup 1.0000x reference)
//
#include <hip/hip_runtime.h>
#include <stdint.h>

// ---------------------------------------------------------------------------
// TransformerBlock on MI355X (gfx950). Runtime dtype detection (fp32 vs bf16
// inputs), bf16-MFMA internal compute, fp32 accumulation + fp32 residual path.
// B=2 S=2048 D=1024 H=16 K=64 MLP=4096; tokens M = 4096.
// R8: attention hybrid MFMA shapes — QK^T via 16x16x32 (b128 K reads),
// PV via 16x16x16 with permuted V staging (b128 V reads), P^T stays in
// registers; l via in-loop adds. GEMMs: register-prefetch double-buffer
// staging (int4 loads one compute-phase ahead) instead of global_load_lds.
// R9: MODE 2/3 gemms get in-block split-K (512 thr, K halves in separate LDS
// staging, padded-LDS combine).
// R10/R11: attn chunk 1024, direct-z for single-chunk tiles, defer-max.
// R12: attn Q-tile 64->128 (512 thr / 8 waves, each wave 16 q-rows as
// before). K/V staging amortized over 2x q-rows; 768 blocks = exactly
// 3/CU -> whole grid co-resident (launch_bounds(512,6)), no imbalance tail.
// Partials only for qt>=8 (512 slots x 16KB); merge 512 thr.
// ---------------------------------------------------------------------------

typedef unsigned short u16;
typedef __bf16 bf16x8 __attribute__((ext_vector_type(8)));
typedef __bf16 bf16x4 __attribute__((ext_vector_type(4)));
typedef __bf16 bf16x2 __attribute__((ext_vector_type(2)));
typedef short  s16x4  __attribute__((ext_vector_type(4)));
typedef float  f32x4  __attribute__((ext_vector_type(4)));

#define QSCALE 0.18033688011112042f   // (1/sqrt(64)) * log2(e): softmax via exp2

__device__ __forceinline__ float bf2f(unsigned int u) {
  union { unsigned int u; float f; } v; v.u = u << 16; return v.f;
}
__device__ __forceinline__ u16 f2bf(float f) {
  union { float f; unsigned int u; } v; v.f = f;
  unsigned int r = v.u + 0x7FFFu + ((v.u >> 16) & 1u);   // RNE
  return (u16)(r >> 16);
}
__device__ __forceinline__ unsigned pkbf(float lo, float hi) {
#if __has_builtin(__builtin_amdgcn_cvt_pk_bf16_f32)
  bf16x2 t = __builtin_amdgcn_cvt_pk_bf16_f32(lo, hi);
  return __builtin_bit_cast(unsigned, t);
#else
  return (unsigned)f2bf(lo) | ((unsigned)f2bf(hi) << 16);
#endif
}
__device__ __forceinline__ float loadf(const void* p, size_t i, int isf) {
  return isf ? ((const float*)p)[i] : bf2f(((const u16*)p)[i]);
}

// 16x16x16 bf16 MFMA wrapper
__device__ __forceinline__ f32x4 mfma16(s16x4 a, s16x4 b, f32x4 c) {
#if __has_builtin(__builtin_amdgcn_mfma_f32_16x16x16_bf16)
  return __builtin_amdgcn_mfma_f32_16x16x16_bf16(
      __builtin_bit_cast(bf16x4, a), __builtin_bit_cast(bf16x4, b), c, 0, 0, 0);
#else
  return __builtin_amdgcn_mfma_f32_16x16x16bf16_1k(a, b, c, 0, 0, 0);
#endif
}

// ---------------------------------------------------------------------------
__global__ __launch_bounds__(256) void detect_dtype(
    const unsigned int* __restrict__ x, int* __restrict__ flag) {
  __shared__ int cnt;
  if (threadIdx.x == 0) cnt = 0;
  __syncthreads();
  int c = 0;
  for (int i = threadIdx.x; i < 512; i += 256) {
    unsigned int e = (x[i] >> 23) & 0xFFu;
    if (e >= 97u && e <= 157u) c++;
  }
  atomicAdd(&cnt, c);
  __syncthreads();
  if (threadIdx.x == 0) *flag = (cnt > 384) ? 1 : 0;
}

// ---------------------------------------------------------------------------
// Tiled transposes: 64x64 tiles through LDS (stride-65 pad -> 2-way = free).
// ---------------------------------------------------------------------------
__global__ __launch_bounds__(256) void pack_qkv_tiled(
    const int* __restrict__ flagp,
    const void* __restrict__ Wq, const void* __restrict__ Wk, const void* __restrict__ Wv,
    u16* __restrict__ WT) {
  __shared__ float t[64][65];
  const int isf = *flagp;
  const int tid = threadIdx.x;
  const int mh = blockIdx.y;            // mat*16 + h
  const int mat = mh >> 4, h = mh & 15;
  const int d0 = blockIdx.x << 6;       // d-tile
  const void* src = (mat == 0) ? Wq : (mat == 1) ? Wk : Wv;
  const float scale = (mat == 0) ? QSCALE : 1.f;
  const int lane = tid & 63, rr = tid >> 6;
  const size_t sbase = ((size_t)h << 16) + lane;
#pragma unroll
  for (int i = 0; i < 16; i++) {
    int d = i * 4 + rr;
    t[d][lane] = loadf(src, sbase + (size_t)(d0 + d) * 64, isf) * scale;
  }
  __syncthreads();
#pragma unroll
  for (int i = 0; i < 16; i++) {
    int k = i * 4 + rr;
    WT[((size_t)((mat << 10) + (h << 6) + k) << 10) + d0 + lane] = f2bf(t[lane][k]);
  }
}

__global__ __launch_bounds__(256) void transpose_tiled(
    const int* __restrict__ flagp, const void* __restrict__ src,
    u16* __restrict__ dst, int R, int C) {
  __shared__ float t[64][65];
  const int isf = *flagp;
  const int tid = threadIdx.x;
  const int c0 = blockIdx.x << 6, r0 = blockIdx.y << 6;
  const int lane = tid & 63, rr = tid >> 6;
#pragma unroll
  for (int i = 0; i < 16; i++) {
    int r = i * 4 + rr;
    t[r][lane] = loadf(src, (size_t)(r0 + r) * C + c0 + lane, isf);
  }
  __syncthreads();
#pragma unroll
  for (int i = 0; i < 16; i++) {
    int c = i * 4 + rr;
    dst[(size_t)(c0 + c) * R + r0 + lane] = f2bf(t[lane][c]);
  }
}

__global__ __launch_bounds__(256) void pack_biases(
    const int* __restrict__ flagp,
    const void* bq, const void* bk, const void* bv,
    const void* bO, const void* bin, const void* bout,
    float* __restrict__ out) {
  const int isf = *flagp;
  int i = blockIdx.x * 256 + threadIdx.x;
  float v;
  if (i < 1024)      v = loadf(bq,   i,        isf) * QSCALE;
  else if (i < 2048) v = loadf(bk,   i - 1024, isf);
  else if (i < 3072) v = loadf(bv,   i - 2048, isf);
  else if (i < 4096) v = loadf(bO,   i - 3072, isf);
  else if (i < 8192) v = loadf(bin,  i - 4096, isf);
  else               v = loadf(bout, i - 8192, isf);
  out[i] = v;
}

// ---------------------------------------------------------------------------
template<int SRC>
__global__ __launch_bounds__(256) void ln_fwd(
    const int* __restrict__ flagp, const void* __restrict__ xin,
    const void* __restrict__ w, const void* __restrict__ b,
    u16* __restrict__ out) {
  const int isf = *flagp;
  const int row = blockIdx.x, tid = threadIdx.x;
  const int col = tid << 2;
  const size_t base = ((size_t)row << 10) + col;
  float v[4];
#pragma unroll
  for (int i = 0; i < 4; i++)
    v[i] = (SRC == 1) ? ((const float*)xin)[base + i] : loadf(xin, base + i, isf);
  float s  = v[0] + v[1] + v[2] + v[3];
  float ss = v[0]*v[0] + v[1]*v[1] + v[2]*v[2] + v[3]*v[3];
#pragma unroll
  for (int mk = 32; mk >= 1; mk >>= 1) {
    s  += __shfl_xor(s,  mk, 64);
    ss += __shfl_xor(ss, mk, 64);
  }
  __shared__ float red[8];
  if ((tid & 63) == 0) { red[tid >> 6] = s; red[4 + (tid >> 6)] = ss; }
  __syncthreads();
  float S  = red[0] + red[1] + red[2] + red[3];
  float SS = red[4] + red[5] + red[6] + red[7];
  float mean = S * (1.f / 1024.f);
  float var  = SS * (1.f / 1024.f) - mean * mean;
  float rstd = rsqrtf(var + 1e-5f);
  u16 e[4];
#pragma unroll
  for (int i = 0; i < 4; i++) {
    float wv = loadf(w, col + i, isf);
    float bv = loadf(b, col + i, isf);
    e[i] = f2bf((v[i] - mean) * rstd * wv + bv);
  }
  uint2 o;
  o.x = (unsigned)e[0] | ((unsigned)e[1] << 16);
  o.y = (unsigned)e[2] | ((unsigned)e[3] << 16);
  *(uint2*)(out + base) = o;
}

// ---------------------------------------------------------------------------
// GEMM C[M,N] = A[M,K] @ BT[N,K]^T + bias. KW*256 threads.
// TM=128: wave tile 64x64 (acc 4x4). TM=64: wave tile 32x64 (acc 2x4).
// KW=2: in-block split-K (wave-group per K half, padded-LDS combine).
// Staging: int4 register prefetch one compute phase ahead.
// XCD-swizzled 1-D grid.
// MODE 1: relu+bf16; 2: +flagged resid -> fp32; 3: +fp32 resid -> flagged out
// MODE 4: QKV epilogue -> q_hm[h][t][64], k_hm, vT[h][f][4096]
// ---------------------------------------------------------------------------
template<int MODE, int TM, int KW>
__global__ __launch_bounds__(KW * 256) void gemm_bt(
    const int* __restrict__ flagp,
    const u16* __restrict__ A, const u16* __restrict__ BT,
    const float* __restrict__ bias, const void* __restrict__ resid,
    void* __restrict__ out, void* __restrict__ out2, void* __restrict__ out3,
    int M, int N, int K, int SHL) {
  constexpr int WR = TM / 32;          // row-frags per wave
  constexpr int ASZ = TM * 32;         // per-group LDS elements (u16)
  constexpr int BSZ = 128 * 32;
  constexpr int STAGE_B = KW * (ASZ + BSZ) * 2;
  constexpr int RED_B = (KW > 1) ? TM * 132 * 4 : 1;   // padded fp32 combine
  constexpr int SMEM_B = STAGE_B > RED_B ? STAGE_B : RED_B;
  __shared__ __align__(16) char smem[SMEM_B];
  u16* as = (u16*)smem;
  u16* bs = (u16*)smem + KW * ASZ;

  int isf = 0;
  if (MODE == 2 || MODE == 3) isf = *flagp;
  const int Lb = blockIdx.x;
  const int xcd = Lb & 7, sidx = Lb >> 3;
  const int SH = 1 << SHL;
  const int by = xcd * SH + (sidx & (SH - 1));
  const int bx = sidx >> SHL;
  const int tid = threadIdx.x;
  const int L = tid & 63, w = tid >> 6;
  const int g = w >> 2, wl = w & 3;    // wave-group (K-split), wave-in-group
  const int wm = (wl >> 1) * (TM >> 1), wn = (wl & 1) << 6;
  const int row0 = by * TM, col0 = bx << 7;
  const int m = L & 15, quad = L >> 4;

  f32x4 zero4 = {0.f, 0.f, 0.f, 0.f};
  f32x4 acc[WR][4];
#pragma unroll
  for (int i = 0; i < WR; i++)
#pragma unroll
    for (int j = 0; j < 4; j++) acc[i][j] = zero4;

  const int KSEG = K / KW;
  const int tl = tid & 255;            // staging id within group
  const int tm = tl >> 2;
  const int tk = (tl & 3) << 3;
  const u16* Ag  = A  + (size_t)(row0 + tm) * K + g * KSEG + tk;
  const u16* Ag2 = Ag + (size_t)64 * K;          // TM==128 only
  const u16* Bg  = BT + (size_t)(col0 + tm) * K + g * KSEG + tk;
  const u16* Bg2 = Bg + (size_t)64 * K;
  u16* asg  = as + g * ASZ;
  u16* bsg  = bs + g * BSZ;
  u16* asl  = asg + tl * 8;
  u16* asl2 = asg + 2048 + tl * 8;
  u16* bsl  = bsg + tl * 8;
  u16* bsl2 = bsg + 2048 + tl * 8;

  const int aoff = (wm + m) * 32 + quad * 8;
  const int boff = (wn + m) * 32 + quad * 8;

  int4 ar0, ar1, br0, br1;
  ar0 = *(const int4*)Ag;
  if (TM == 128) ar1 = *(const int4*)Ag2;
  br0 = *(const int4*)Bg;
  br1 = *(const int4*)Bg2;

  for (int kk = 0; kk < KSEG; kk += 32) {
    __syncthreads();                    // LDS consumers of prev step done
    *(int4*)asl = ar0;
    if (TM == 128) *(int4*)asl2 = ar1;
    *(int4*)bsl = br0;
    *(int4*)bsl2 = br1;
    __syncthreads();
    if (kk + 32 < KSEG) {               // prefetch next step into registers
      ar0 = *(const int4*)(Ag + kk + 32);
      if (TM == 128) ar1 = *(const int4*)(Ag2 + kk + 32);
      br0 = *(const int4*)(Bg + kk + 32);
      br1 = *(const int4*)(Bg2 + kk + 32);
    }
    bf16x8 af[WR], bfr[4];
#pragma unroll
    for (int i = 0; i < WR; i++) af[i]  = *(const bf16x8*)&asg[aoff + i * 512];
#pragma unroll
    for (int j = 0; j < 4; j++) bfr[j] = *(const bf16x8*)&bsg[boff + j * 512];
#pragma unroll
    for (int i = 0; i < WR; i++)
#pragma unroll
      for (int j = 0; j < 4; j++)
        acc[i][j] = __builtin_amdgcn_mfma_f32_16x16x32_bf16(af[i], bfr[j], acc[i][j], 0, 0, 0);
  }

  if (KW > 1) {
    // combine group 1's accumulators into group 0 through padded LDS.
    __syncthreads();                    // staging LDS dead from here
    float* red = (float*)smem;
    if (g == 1) {
#pragma unroll
      for (int i = 0; i < WR; i++)
#pragma unroll
        for (int j = 0; j < 4; j++)
#pragma unroll
          for (int r = 0; r < 4; r++)
            red[(wm + i * 16 + quad * 4 + r) * 132 + wn + j * 16 + m] = acc[i][j][r];
    }
    __syncthreads();
    if (g == 0) {
#pragma unroll
      for (int i = 0; i < WR; i++)
#pragma unroll
        for (int j = 0; j < 4; j++)
#pragma unroll
          for (int r = 0; r < 4; r++)
            acc[i][j][r] += red[(wm + i * 16 + quad * 4 + r) * 132 + wn + j * 16 + m];
    }
  }

  if (g == 0) {
#pragma unroll
    for (int j = 0; j < 4; j++) {
      const int col = col0 + wn + j * 16 + m;
      const float bval = bias[col];
      if (MODE == 4) {
        const int sel = col >> 10;
        const int hh  = (col >> 6) & 15;
        const int f   = col & 63;
#pragma unroll
        for (int i = 0; i < WR; i++) {
          const int rowb = row0 + wm + i * 16 + quad * 4;
          if (sel < 2) {
            u16* dst = (u16*)(sel ? out2 : out);
#pragma unroll
            for (int r = 0; r < 4; r++)
              dst[((((size_t)hh << 12) + rowb + r) << 6) + f] = f2bf(acc[i][j][r] + bval);
          } else {
            uint2 o;
            o.x = pkbf(acc[i][j][0] + bval, acc[i][j][1] + bval);
            o.y = pkbf(acc[i][j][2] + bval, acc[i][j][3] + bval);
            *(uint2*)&((u16*)out3)[(((size_t)hh * 64 + f) << 12) + rowb] = o;
          }
        }
      } else {
#pragma unroll
        for (int i = 0; i < WR; i++) {
          const int rowb = row0 + wm + i * 16 + quad * 4;
#pragma unroll
          for (int r = 0; r < 4; r++) {
            float vv = acc[i][j][r] + bval;
            size_t idx = (size_t)(rowb + r) * N + col;
            if (MODE == 1) {
              ((u16*)out)[idx] = f2bf(fmaxf(vv, 0.f));
            } else if (MODE == 2) {
              ((float*)out)[idx] = vv + loadf(resid, idx, isf);
            } else if (MODE == 3) {
              float o = vv + ((const float*)resid)[idx];
              if (isf) ((float*)out)[idx] = o;
              else     ((u16*)out)[idx]   = f2bf(o);
            }
          }
        }
      }
    }
  }
}

// ---------------------------------------------------------------------------
// Flash attention, split-K, hybrid-MFMA transposed form. R12: 128-q tiles.
// Block = (combo=h*2+b, qt128, ci): 128 q (8 waves x 16, q = lane&15 column)
// vs k-chunk <=1024 (<=8 steps of 128). 768 blocks = 3/CU, all co-resident.
// QK^T: S^T = K·Q^T via 16x16x32 (K A-frags contiguous 16B -> ds_read_b128).
// P^T stays in registers, feeds O^T = V^T·P^T via 16x16x16; V staged
// PERMUTED (c' = quad*32 + kt*4 + j) so PV A-frags are b128 reads.
// Defer-max: skip O-rescale while per-step max growth <= 8 (exp2 domain).
// Tiles with nc==1 (qt<=7) normalize in-kernel and write z directly.
// ---------------------------------------------------------------------------
__global__ __launch_bounds__(512, 6) void attn_part(
    const u16* __restrict__ qh, const u16* __restrict__ kh,
    const u16* __restrict__ vT, u16* __restrict__ Opart,
    float* __restrict__ stats, u16* __restrict__ z) {
  const int combo = blockIdx.x;      // h*2 + b
  const int qt = blockIdx.y;         // 0..15 (128-row q-tiles)
  const int ci = blockIdx.z;         // 0..1 (1024-chunks)
  const int q0 = qt << 7;
  const int nc = (q0 + 128 + 1023) >> 10;
  if (ci >= nc) return;
  const int k_lo = ci << 10;
  const int k_hi = min(k_lo + 1024, q0 + 128);
  const int nsteps = (k_hi - k_lo + 127) >> 7;

  __shared__ u16 kS[128 * 72];       // K tile [tok][64+8 pad]; reused as O bounce
  __shared__ u16 vS[64 * 136];       // V^T tile [f][128 permuted + 8 pad]
  const int tid = threadIdx.x, L = tid & 63, w = tid >> 6;   // w 0..7
  const int m = L & 15, quad = L >> 4;
  const int h = combo >> 1, b = combo & 1;
  const size_t tb = (size_t)b * 2048;
  const size_t hbase = (size_t)h * 4096;
  const int qg = q0 + w * 16 + m;    // this lane's global q (column)

  // Q as 16x16x32 B-frags: lane n=q, k=feat quad*8+j (two 32-feat chunks)
  bf16x8 qb0, qb1;
  {
    const u16* qp = qh + ((hbase + tb + (size_t)qg) << 6) + quad * 8;
    qb0 = *(const bf16x8*)qp;
    qb1 = *(const bf16x8*)(qp + 32);
  }

  f32x4 zero4 = {0.f, 0.f, 0.f, 0.f};
  f32x4 O[4];                        // O^T: lane q, f = ft*16 + quad*4 + r
#pragma unroll
  for (int ft = 0; ft < 4; ft++) O[ft] = zero4;
  float mrow = -30000.f, lrow = 0.f;

  // staging: 512 thr, K tile 128x64 (1024 int4, 2 per thread),
  // V tile 64x128 (1024 int4, 2 per thread)
  const int krow[2] = { (0*512+tid) >> 3, (1*512+tid) >> 3 };
  const int kc = tid & 7;
  const int vf[2] = { (0*512+tid) >> 4, (1*512+tid) >> 4 };
  const int vc = tid & 15;
  // permuted V column bases for the two 4-elem halves of each int4
  const int vq = (vc & 1) << 1;             // quad base 2*(vc&1)
  const int vk4 = (vc >> 1) << 2;           // kt*4
  const int vc0 = (vq << 5) + vk4;          // quad*32 + kt*4
  const int vc1 = ((vq + 1) << 5) + vk4;

  int4 kr[2], vr[2];
#pragma unroll
  for (int i = 0; i < 2; i++) {
    kr[i] = *(const int4*)(kh + ((hbase + tb + k_lo + krow[i]) << 6) + kc * 8);
    vr[i] = *(const int4*)(vT + (((size_t)h * 64 + vf[i]) << 12) + tb + k_lo + vc * 8);
  }

  for (int j = 0; j < nsteps; j++) {
    const int k0 = k_lo + (j << 7);
    __syncthreads();
#pragma unroll
    for (int i = 0; i < 2; i++) {
      *(int4*)&kS[krow[i] * 72 + kc * 8] = kr[i];
      union { int4 v; s16x4 hh[2]; } tv; tv.v = vr[i];
      *(s16x4*)&vS[vf[i] * 136 + vc0] = tv.hh[0];
      *(s16x4*)&vS[vf[i] * 136 + vc1] = tv.hh[1];
    }
    __syncthreads();
    if (j + 1 < nsteps) {
      const int k1 = k_lo + ((j + 1) << 7);
#pragma unroll
      for (int i = 0; i < 2; i++) {
        kr[i] = *(const int4*)(kh + ((hbase + tb + k1 + krow[i]) << 6) + kc * 8);
        vr[i] = *(const int4*)(vT + (((size_t)h * 64 + vf[i]) << 12) + tb + k1 + vc * 8);
      }
    }
    // S^T = K·Q^T via 16x16x32: lane col q=m, rows ktok = kt*16 + quad*4 + r
    f32x4 sc[8];
#pragma unroll
    for (int kt = 0; kt < 8; kt++) {
      const u16* kp = &kS[(kt * 16 + m) * 72 + quad * 8];
      bf16x8 ka0 = *(const bf16x8*)kp;
      bf16x8 ka1 = *(const bf16x8*)(kp + 32);
      f32x4 t = zero4;
      t = __builtin_amdgcn_mfma_f32_16x16x32_bf16(ka0, qb0, t, 0, 0, 0);
      t = __builtin_amdgcn_mfma_f32_16x16x32_bf16(ka1, qb1, t, 0, 0, 0);
      sc[kt] = t;
    }
    if (k0 + 128 > q0) {   // touches diagonal region: causal mask
#pragma unroll
      for (int kt = 0; kt < 8; kt++)
#pragma unroll
        for (int r = 0; r < 4; r++) {
          int ktok = k0 + kt * 16 + quad * 4 + r;
          if (ktok > qg) sc[kt][r] = -30000.f;
        }
    }
    // per-lane max over 32 regs + 2 shuffles (q fixed per lane)
    float mx = sc[0][0];
#pragma unroll
    for (int kt = 0; kt < 8; kt++)
#pragma unroll
      for (int r = 0; r < 4; r++) mx = fmaxf(mx, sc[kt][r]);
    mx = fmaxf(mx, __shfl_xor(mx, 16, 64));
    mx = fmaxf(mx, __shfl_xor(mx, 32, 64));
    // defer-max (T13): only rescale when max grew by > 8 (exp2 domain)
    if (!__all(mx <= mrow + 8.f)) {
      float mnew = fmaxf(mrow, mx);
      float alpha = __builtin_amdgcn_exp2f(mrow - mnew);
      lrow *= alpha;
#pragma unroll
      for (int ft = 0; ft < 4; ft++) O[ft] *= alpha;
      mrow = mnew;
    }
    // P^T = exp2(S^T - m): pack to bf16 B-frags; accumulate l inline
    s16x4 pb[8];
    float sum = 0.f;
#pragma unroll
    for (int kt = 0; kt < 8; kt++) {
      float e0 = __builtin_amdgcn_exp2f(sc[kt][0] - mrow);
      float e1 = __builtin_amdgcn_exp2f(sc[kt][1] - mrow);
      float e2 = __builtin_amdgcn_exp2f(sc[kt][2] - mrow);
      float e3 = __builtin_amdgcn_exp2f(sc[kt][3] - mrow);
      sum += (e0 + e1) + (e2 + e3);
      union { uint2 u; s16x4 hh; } pu;
      pu.u.x = pkbf(e0, e1);
      pu.u.y = pkbf(e2, e3);
      pb[kt] = pu.hh;
    }
    sum += __shfl_xor(sum, 16, 64);
    sum += __shfl_xor(sum, 32, 64);
    lrow += sum;
    // O^T += V^T·P^T via 16x16x16; V A-frags read b128 (2 frags per read)
#pragma unroll
    for (int ft = 0; ft < 4; ft++) {
      const u16* vp = &vS[(ft * 16 + m) * 136 + quad * 32];
#pragma unroll
      for (int pr = 0; pr < 4; pr++) {
        union { bf16x8 v; s16x4 hh[2]; } u;
        u.v = *(const bf16x8*)(vp + pr * 8);
        O[ft] = mfma16(u.hh[0], pb[2 * pr],     O[ft]);
        O[ft] = mfma16(u.hh[1], pb[2 * pr + 1], O[ft]);
      }
    }
  }

  // nc==1: normalize in-kernel (diagonal guarantees lrow > 0)
  if (nc == 1) {
    float inv = 1.f / lrow;
#pragma unroll
    for (int ft = 0; ft < 4; ft++) O[ft] *= inv;
  }

  // O^T -> LDS bounce (kS reused, 128 rows x 64f) -> coalesced global stores
  __syncthreads();
#pragma unroll
  for (int ft = 0; ft < 4; ft++) {
    union { uint2 u; s16x4 hh; } o4;
    o4.u.x = pkbf(O[ft][0], O[ft][1]);
    o4.u.y = pkbf(O[ft][2], O[ft][3]);
    *(s16x4*)&kS[(w * 16 + m) * 72 + ft * 16 + quad * 4] = o4.hh;
  }
  __syncthreads();
  if (nc == 1) {
    // direct z write: [tok][1024] layout, this head's 64-col stripe
    u16* zp = z + ((tb + (size_t)q0) << 10) + h * 64;
#pragma unroll
    for (int it = 0; it < 2; it++) {
      int idx = it * 512 + tid;
      int row = idx >> 3, c = idx & 7;
      *(int4*)&zp[((size_t)row << 10) + c * 8] = *(const int4*)&kS[row * 72 + c * 8];
    }
  } else {
    const int slot = (combo * 16 + qt) * 2 + ci;
    u16* op = Opart + ((size_t)slot << 13);
#pragma unroll
    for (int it = 0; it < 2; it++) {
      int idx = it * 512 + tid;
      int row = idx >> 3, c = idx & 7;
      *(int4*)&op[row * 64 + c * 8] = *(const int4*)&kS[row * 72 + c * 8];
    }
    if (quad == 0) {
      stats[slot * 256 + w * 16 + m]       = mrow;
      stats[slot * 256 + 128 + w * 16 + m] = lrow;
    }
  }
}

// merge partials -> z [t][1024]; only qt>=8 tiles (nc==2) reach here. 512 thr.
__global__ __launch_bounds__(512) void attn_merge(
    const u16* __restrict__ Opart, const float* __restrict__ stats,
    u16* __restrict__ z) {
  const int combo = blockIdx.x, qt = 8 + blockIdx.y;
  const int h = combo >> 1, b = combo & 1;
  const int q0 = qt << 7;
  const int tid = threadIdx.x;
  const int t = tid >> 2, f0 = (tid & 3) << 4;   // t 0..127
  const int slot0 = (combo * 16 + qt) * 2;
  float M = fmaxf(stats[slot0 * 256 + t], stats[(slot0 + 1) * 256 + t]);
  float acc[16];
#pragma unroll
  for (int e = 0; e < 16; e++) acc[e] = 0.f;
  float ltot = 0.f;
#pragma unroll
  for (int ci = 0; ci < 2; ci++) {
    float mi = stats[(slot0 + ci) * 256 + t];
    float li = stats[(slot0 + ci) * 256 + 128 + t];
    float wgt = exp2f(mi - M);
    ltot += wgt * li;
    const u16* op = Opart + (((size_t)(slot0 + ci)) << 13) + t * 64 + f0;
    union { int4 v; u16 u[8]; } a0, a1;
    a0.v = *(const int4*)op;
    a1.v = *(const int4*)(op + 8);
#pragma unroll
    for (int e = 0; e < 8; e++) {
      acc[e]     += wgt * bf2f(a0.u[e]);
      acc[8 + e] += wgt * bf2f(a1.u[e]);
    }
  }
  float inv = 1.f / ltot;
  union { int4 v; u16 u[8]; } o0, o1;
#pragma unroll
  for (int e = 0; e < 8; e++) {
    o0.u[e] = f2bf(acc[e] * inv);
    o1.u[e] = f2bf(acc[8 + e] * inv);
  }
  size_t tok = (size_t)b * 2048 + q0 + t;
  *(int4*)&z[tok * 1024 + h * 64 + f0]     = o0.v;
  *(int4*)&z[tok * 1024 + h * 64 + f0 + 8] = o1.v;
}

// ---------------------------------------------------------------------------
extern "C" void kernel_launch(void* const* d_in, const int* in_sizes, int n_in,
                              void* d_out, int out_size, void* d_ws, size_t ws_size,
                              hipStream_t stream) {
  (void)in_sizes; (void)n_in; (void)out_size; (void)ws_size;
  const void* resid_pre = d_in[0];
  const void* ln1_w = d_in[1];
  const void* ln1_b = d_in[2];
  const void* W_Q   = d_in[3];
  const void* b_Q   = d_in[4];
  const void* W_K   = d_in[5];
  const void* b_K   = d_in[6];
  const void* W_V   = d_in[7];
  const void* b_V   = d_in[8];
  const void* W_O   = d_in[9];
  const void* b_O   = d_in[10];
  const void* ln2_w = d_in[11];
  const void* ln2_b = d_in[12];
  const void* W_in  = d_in[13];
  const void* b_in  = d_in[14];
  const void* W_out = d_in[15];
  const void* b_out = d_in[16];

  char* p = (char*)d_ws;
  auto alloc = [&](size_t bytes) {
    char* r = p; p += (bytes + 255) & ~(size_t)255; return (void*)r;
  };
  int*   flag      = (int*)  alloc(256);
  u16*   WqkvT     = (u16*)  alloc(3072ull * 1024 * 2);
  u16*   WoT       = (u16*)  alloc(1024ull * 1024 * 2);
  u16*   WinT      = (u16*)  alloc(4096ull * 1024 * 2);
  u16*   WoutT     = (u16*)  alloc(1024ull * 4096 * 2);
  float* biases    = (float*)alloc(9216 * 4);
  u16*   xn        = (u16*)  alloc(4096ull * 1024 * 2);  // reused as z
  u16*   q_hm      = (u16*)  alloc(16ull * 4096 * 64 * 2);
  u16*   k_hm      = (u16*)  alloc(16ull * 4096 * 64 * 2);
  u16*   vTws      = (u16*)  alloc(16ull * 64 * 4096 * 2);
  float* resid_mid = (float*)alloc(4096ull * 1024 * 4);
  u16*   h2        = (u16*)  alloc(4096ull * 1024 * 2);  // attn stats before ln2
  u16*   act       = (u16*)  alloc(4096ull * 4096 * 2);  // attn partials before MLP
  u16*   z = xn;
  u16*   Opart = act;              // 1024 slots x 16 KB = 16 MB (< 32 MB)
  float* stats = (float*)h2;       // 1024 slots x 256 fp32 = 1 MB < 8 MB

  detect_dtype<<<1, 256, 0, stream>>>((const unsigned int*)resid_pre, flag);

  pack_qkv_tiled<<<dim3(16, 48), 256, 0, stream>>>(flag, W_Q, W_K, W_V, WqkvT);
  transpose_tiled<<<dim3(16, 16), 256, 0, stream>>>(flag, W_O,   WoT,   1024, 1024);
  transpose_tiled<<<dim3(64, 16), 256, 0, stream>>>(flag, W_in,  WinT,  1024, 4096);
  transpose_tiled<<<dim3(16, 64), 256, 0, stream>>>(flag, W_out, WoutT, 4096, 1024);
  pack_biases<<<36, 256, 0, stream>>>(flag, b_Q, b_K, b_V, b_O, b_in, b_out, biases);

  ln_fwd<0><<<4096, 256, 0, stream>>>(flag, resid_pre, ln1_w, ln1_b, xn);
  // qkv -> head-major q/k + transposed v. grid: 8 XCD x SH=4 rows x 24 cols
  gemm_bt<4, 128, 1><<<768, 256, 0, stream>>>(
      flag, xn, WqkvT, biases, nullptr, q_hm, k_hm, vTws, 4096, 3072, 1024, 2);
  // split-K causal flash attention (128-q tiles, 1024-chunks) -> z
  attn_part<<<dim3(32, 16, 2), 512, 0, stream>>>(q_hm, k_hm, vTws, Opart, stats, z);
  attn_merge<<<dim3(32, 8), 512, 0, stream>>>(Opart, stats, z);
  // resid_mid = resid_pre + z @ W_O + b_O   (fp32). 8 XCD x SH=8 x 8 cols,
  // in-block split-K (512 thr)
  gemm_bt<2, 64, 2><<<512, 512, 0, stream>>>(
      flag, z, WoT, biases + 3072, resid_pre, resid_mid, nullptr, nullptr, 4096, 1024, 1024, 3);
  ln_fwd<1><<<4096, 256, 0, stream>>>(flag, resid_mid, ln2_w, ln2_b, h2);
  // act = relu(h2 @ W_in + b_in). 8 XCD x SH=4 x 32 cols
  gemm_bt<1, 128, 1><<<1024, 256, 0, stream>>>(
      flag, h2, WinT, biases + 4096, nullptr, act, nullptr, nullptr, 4096, 4096, 1024, 2);
  // out = resid_mid + act @ W_out + b_out. 8 XCD x SH=8 x 8 cols,
  // in-block split-K (512 thr)
  gemm_bt<3, 64, 2><<<512, 512, 0, stream>>>(
      flag, act, WoutT, biases + 8192, resid_mid, d_out, nullptr, nullptr, 4096, 1024, 4096, 3);
}

// Round 5
// 438.720 us; speedup vs baseline: 1.0343x; 1.0343x over previous
//
#include <hip/hip_runtime.h>
#include <stdint.h>

// ---------------------------------------------------------------------------
// TransformerBlock on MI355X (gfx950). Runtime dtype detection (fp32 vs bf16
// inputs), bf16-MFMA internal compute, fp32 accumulation + fp32 residual path.
// B=2 S=2048 D=1024 H=16 K=64 MLP=4096; tokens M = 4096.
// R8: attention hybrid MFMA shapes — QK^T via 16x16x32 (b128 K reads),
// PV via 16x16x16 with permuted V staging (b128 V reads).
// R9: MODE 2/3 gemms get in-block split-K (512 thr, padded-LDS combine).
// R10/R11: attn chunk 1024, direct-z for single-chunk tiles, defer-max.
// R12: attn Q-tile 128 (512 thr / 8 waves), amortized K/V staging.
//   LESSON: launch_bounds(512,6) forced VGPR to 40 vs ~90 demand -> scratch
//   spill; WRITE_SIZE 157MB vs 16MB model; kernel became spill-traffic-bound.
//   (R9/R11 were also spilling: WRITE 91-98MB vs model.)
// R13: fit the 64-VGPR tier GENUINELY: (a) 128-token step split into two
// 64-token halves so the score array is sc[4]=16 VGPR not sc[8]=32;
// (b) JIT K/V loads (no cross-phase prefetch regs; loads issue before the
// barrier, 4 blocks/CU TLP covers latency); (c) launch_bounds(512,8).
// 4 blocks/CU x 8 waves = 32 waves/CU, zero scratch.
// ---------------------------------------------------------------------------

typedef unsigned short u16;
typedef __bf16 bf16x8 __attribute__((ext_vector_type(8)));
typedef __bf16 bf16x4 __attribute__((ext_vector_type(4)));
typedef __bf16 bf16x2 __attribute__((ext_vector_type(2)));
typedef short  s16x4  __attribute__((ext_vector_type(4)));
typedef float  f32x4  __attribute__((ext_vector_type(4)));

#define QSCALE 0.18033688011112042f   // (1/sqrt(64)) * log2(e): softmax via exp2

__device__ __forceinline__ float bf2f(unsigned int u) {
  union { unsigned int u; float f; } v; v.u = u << 16; return v.f;
}
__device__ __forceinline__ u16 f2bf(float f) {
  union { float f; unsigned int u; } v; v.f = f;
  unsigned int r = v.u + 0x7FFFu + ((v.u >> 16) & 1u);   // RNE
  return (u16)(r >> 16);
}
__device__ __forceinline__ unsigned pkbf(float lo, float hi) {
#if __has_builtin(__builtin_amdgcn_cvt_pk_bf16_f32)
  bf16x2 t = __builtin_amdgcn_cvt_pk_bf16_f32(lo, hi);
  return __builtin_bit_cast(unsigned, t);
#else
  return (unsigned)f2bf(lo) | ((unsigned)f2bf(hi) << 16);
#endif
}
__device__ __forceinline__ float loadf(const void* p, size_t i, int isf) {
  return isf ? ((const float*)p)[i] : bf2f(((const u16*)p)[i]);
}

// 16x16x16 bf16 MFMA wrapper
__device__ __forceinline__ f32x4 mfma16(s16x4 a, s16x4 b, f32x4 c) {
#if __has_builtin(__builtin_amdgcn_mfma_f32_16x16x16_bf16)
  return __builtin_amdgcn_mfma_f32_16x16x16_bf16(
      __builtin_bit_cast(bf16x4, a), __builtin_bit_cast(bf16x4, b), c, 0, 0, 0);
#else
  return __builtin_amdgcn_mfma_f32_16x16x16bf16_1k(a, b, c, 0, 0, 0);
#endif
}

// ---------------------------------------------------------------------------
__global__ __launch_bounds__(256) void detect_dtype(
    const unsigned int* __restrict__ x, int* __restrict__ flag) {
  __shared__ int cnt;
  if (threadIdx.x == 0) cnt = 0;
  __syncthreads();
  int c = 0;
  for (int i = threadIdx.x; i < 512; i += 256) {
    unsigned int e = (x[i] >> 23) & 0xFFu;
    if (e >= 97u && e <= 157u) c++;
  }
  atomicAdd(&cnt, c);
  __syncthreads();
  if (threadIdx.x == 0) *flag = (cnt > 384) ? 1 : 0;
}

// ---------------------------------------------------------------------------
// Tiled transposes: 64x64 tiles through LDS (stride-65 pad -> 2-way = free).
// ---------------------------------------------------------------------------
__global__ __launch_bounds__(256) void pack_qkv_tiled(
    const int* __restrict__ flagp,
    const void* __restrict__ Wq, const void* __restrict__ Wk, const void* __restrict__ Wv,
    u16* __restrict__ WT) {
  __shared__ float t[64][65];
  const int isf = *flagp;
  const int tid = threadIdx.x;
  const int mh = blockIdx.y;            // mat*16 + h
  const int mat = mh >> 4, h = mh & 15;
  const int d0 = blockIdx.x << 6;       // d-tile
  const void* src = (mat == 0) ? Wq : (mat == 1) ? Wk : Wv;
  const float scale = (mat == 0) ? QSCALE : 1.f;
  const int lane = tid & 63, rr = tid >> 6;
  const size_t sbase = ((size_t)h << 16) + lane;
#pragma unroll
  for (int i = 0; i < 16; i++) {
    int d = i * 4 + rr;
    t[d][lane] = loadf(src, sbase + (size_t)(d0 + d) * 64, isf) * scale;
  }
  __syncthreads();
#pragma unroll
  for (int i = 0; i < 16; i++) {
    int k = i * 4 + rr;
    WT[((size_t)((mat << 10) + (h << 6) + k) << 10) + d0 + lane] = f2bf(t[lane][k]);
  }
}

__global__ __launch_bounds__(256) void transpose_tiled(
    const int* __restrict__ flagp, const void* __restrict__ src,
    u16* __restrict__ dst, int R, int C) {
  __shared__ float t[64][65];
  const int isf = *flagp;
  const int tid = threadIdx.x;
  const int c0 = blockIdx.x << 6, r0 = blockIdx.y << 6;
  const int lane = tid & 63, rr = tid >> 6;
#pragma unroll
  for (int i = 0; i < 16; i++) {
    int r = i * 4 + rr;
    t[r][lane] = loadf(src, (size_t)(r0 + r) * C + c0 + lane, isf);
  }
  __syncthreads();
#pragma unroll
  for (int i = 0; i < 16; i++) {
    int c = i * 4 + rr;
    dst[(size_t)(c0 + c) * R + r0 + lane] = f2bf(t[lane][c]);
  }
}

__global__ __launch_bounds__(256) void pack_biases(
    const int* __restrict__ flagp,
    const void* bq, const void* bk, const void* bv,
    const void* bO, const void* bin, const void* bout,
    float* __restrict__ out) {
  const int isf = *flagp;
  int i = blockIdx.x * 256 + threadIdx.x;
  float v;
  if (i < 1024)      v = loadf(bq,   i,        isf) * QSCALE;
  else if (i < 2048) v = loadf(bk,   i - 1024, isf);
  else if (i < 3072) v = loadf(bv,   i - 2048, isf);
  else if (i < 4096) v = loadf(bO,   i - 3072, isf);
  else if (i < 8192) v = loadf(bin,  i - 4096, isf);
  else               v = loadf(bout, i - 8192, isf);
  out[i] = v;
}

// ---------------------------------------------------------------------------
template<int SRC>
__global__ __launch_bounds__(256) void ln_fwd(
    const int* __restrict__ flagp, const void* __restrict__ xin,
    const void* __restrict__ w, const void* __restrict__ b,
    u16* __restrict__ out) {
  const int isf = *flagp;
  const int row = blockIdx.x, tid = threadIdx.x;
  const int col = tid << 2;
  const size_t base = ((size_t)row << 10) + col;
  float v[4];
#pragma unroll
  for (int i = 0; i < 4; i++)
    v[i] = (SRC == 1) ? ((const float*)xin)[base + i] : loadf(xin, base + i, isf);
  float s  = v[0] + v[1] + v[2] + v[3];
  float ss = v[0]*v[0] + v[1]*v[1] + v[2]*v[2] + v[3]*v[3];
#pragma unroll
  for (int mk = 32; mk >= 1; mk >>= 1) {
    s  += __shfl_xor(s,  mk, 64);
    ss += __shfl_xor(ss, mk, 64);
  }
  __shared__ float red[8];
  if ((tid & 63) == 0) { red[tid >> 6] = s; red[4 + (tid >> 6)] = ss; }
  __syncthreads();
  float S  = red[0] + red[1] + red[2] + red[3];
  float SS = red[4] + red[5] + red[6] + red[7];
  float mean = S * (1.f / 1024.f);
  float var  = SS * (1.f / 1024.f) - mean * mean;
  float rstd = rsqrtf(var + 1e-5f);
  u16 e[4];
#pragma unroll
  for (int i = 0; i < 4; i++) {
    float wv = loadf(w, col + i, isf);
    float bv = loadf(b, col + i, isf);
    e[i] = f2bf((v[i] - mean) * rstd * wv + bv);
  }
  uint2 o;
  o.x = (unsigned)e[0] | ((unsigned)e[1] << 16);
  o.y = (unsigned)e[2] | ((unsigned)e[3] << 16);
  *(uint2*)(out + base) = o;
}

// ---------------------------------------------------------------------------
// GEMM C[M,N] = A[M,K] @ BT[N,K]^T + bias. KW*256 threads.
// TM=128: wave tile 64x64 (acc 4x4). TM=64: wave tile 32x64 (acc 2x4).
// KW=2: in-block split-K (wave-group per K half, padded-LDS combine).
// Staging: int4 register prefetch one compute phase ahead.
// XCD-swizzled 1-D grid.
// MODE 1: relu+bf16; 2: +flagged resid -> fp32; 3: +fp32 resid -> flagged out
// MODE 4: QKV epilogue -> q_hm[h][t][64], k_hm, vT[h][f][4096]
// ---------------------------------------------------------------------------
template<int MODE, int TM, int KW>
__global__ __launch_bounds__(KW * 256) void gemm_bt(
    const int* __restrict__ flagp,
    const u16* __restrict__ A, const u16* __restrict__ BT,
    const float* __restrict__ bias, const void* __restrict__ resid,
    void* __restrict__ out, void* __restrict__ out2, void* __restrict__ out3,
    int M, int N, int K, int SHL) {
  constexpr int WR = TM / 32;          // row-frags per wave
  constexpr int ASZ = TM * 32;         // per-group LDS elements (u16)
  constexpr int BSZ = 128 * 32;
  constexpr int STAGE_B = KW * (ASZ + BSZ) * 2;
  constexpr int RED_B = (KW > 1) ? TM * 132 * 4 : 1;   // padded fp32 combine
  constexpr int SMEM_B = STAGE_B > RED_B ? STAGE_B : RED_B;
  __shared__ __align__(16) char smem[SMEM_B];
  u16* as = (u16*)smem;
  u16* bs = (u16*)smem + KW * ASZ;

  int isf = 0;
  if (MODE == 2 || MODE == 3) isf = *flagp;
  const int Lb = blockIdx.x;
  const int xcd = Lb & 7, sidx = Lb >> 3;
  const int SH = 1 << SHL;
  const int by = xcd * SH + (sidx & (SH - 1));
  const int bx = sidx >> SHL;
  const int tid = threadIdx.x;
  const int L = tid & 63, w = tid >> 6;
  const int g = w >> 2, wl = w & 3;    // wave-group (K-split), wave-in-group
  const int wm = (wl >> 1) * (TM >> 1), wn = (wl & 1) << 6;
  const int row0 = by * TM, col0 = bx << 7;
  const int m = L & 15, quad = L >> 4;

  f32x4 zero4 = {0.f, 0.f, 0.f, 0.f};
  f32x4 acc[WR][4];
#pragma unroll
  for (int i = 0; i < WR; i++)
#pragma unroll
    for (int j = 0; j < 4; j++) acc[i][j] = zero4;

  const int KSEG = K / KW;
  const int tl = tid & 255;            // staging id within group
  const int tm = tl >> 2;
  const int tk = (tl & 3) << 3;
  const u16* Ag  = A  + (size_t)(row0 + tm) * K + g * KSEG + tk;
  const u16* Ag2 = Ag + (size_t)64 * K;          // TM==128 only
  const u16* Bg  = BT + (size_t)(col0 + tm) * K + g * KSEG + tk;
  const u16* Bg2 = Bg + (size_t)64 * K;
  u16* asg  = as + g * ASZ;
  u16* bsg  = bs + g * BSZ;
  u16* asl  = asg + tl * 8;
  u16* asl2 = asg + 2048 + tl * 8;
  u16* bsl  = bsg + tl * 8;
  u16* bsl2 = bsg + 2048 + tl * 8;

  const int aoff = (wm + m) * 32 + quad * 8;
  const int boff = (wn + m) * 32 + quad * 8;

  int4 ar0, ar1, br0, br1;
  ar0 = *(const int4*)Ag;
  if (TM == 128) ar1 = *(const int4*)Ag2;
  br0 = *(const int4*)Bg;
  br1 = *(const int4*)Bg2;

  for (int kk = 0; kk < KSEG; kk += 32) {
    __syncthreads();                    // LDS consumers of prev step done
    *(int4*)asl = ar0;
    if (TM == 128) *(int4*)asl2 = ar1;
    *(int4*)bsl = br0;
    *(int4*)bsl2 = br1;
    __syncthreads();
    if (kk + 32 < KSEG) {               // prefetch next step into registers
      ar0 = *(const int4*)(Ag + kk + 32);
      if (TM == 128) ar1 = *(const int4*)(Ag2 + kk + 32);
      br0 = *(const int4*)(Bg + kk + 32);
      br1 = *(const int4*)(Bg2 + kk + 32);
    }
    bf16x8 af[WR], bfr[4];
#pragma unroll
    for (int i = 0; i < WR; i++) af[i]  = *(const bf16x8*)&asg[aoff + i * 512];
#pragma unroll
    for (int j = 0; j < 4; j++) bfr[j] = *(const bf16x8*)&bsg[boff + j * 512];
#pragma unroll
    for (int i = 0; i < WR; i++)
#pragma unroll
      for (int j = 0; j < 4; j++)
        acc[i][j] = __builtin_amdgcn_mfma_f32_16x16x32_bf16(af[i], bfr[j], acc[i][j], 0, 0, 0);
  }

  if (KW > 1) {
    // combine group 1's accumulators into group 0 through padded LDS.
    __syncthreads();                    // staging LDS dead from here
    float* red = (float*)smem;
    if (g == 1) {
#pragma unroll
      for (int i = 0; i < WR; i++)
#pragma unroll
        for (int j = 0; j < 4; j++)
#pragma unroll
          for (int r = 0; r < 4; r++)
            red[(wm + i * 16 + quad * 4 + r) * 132 + wn + j * 16 + m] = acc[i][j][r];
    }
    __syncthreads();
    if (g == 0) {
#pragma unroll
      for (int i = 0; i < WR; i++)
#pragma unroll
        for (int j = 0; j < 4; j++)
#pragma unroll
          for (int r = 0; r < 4; r++)
            acc[i][j][r] += red[(wm + i * 16 + quad * 4 + r) * 132 + wn + j * 16 + m];
    }
  }

  if (g == 0) {
#pragma unroll
    for (int j = 0; j < 4; j++) {
      const int col = col0 + wn + j * 16 + m;
      const float bval = bias[col];
      if (MODE == 4) {
        const int sel = col >> 10;
        const int hh  = (col >> 6) & 15;
        const int f   = col & 63;
#pragma unroll
        for (int i = 0; i < WR; i++) {
          const int rowb = row0 + wm + i * 16 + quad * 4;
          if (sel < 2) {
            u16* dst = (u16*)(sel ? out2 : out);
#pragma unroll
            for (int r = 0; r < 4; r++)
              dst[((((size_t)hh << 12) + rowb + r) << 6) + f] = f2bf(acc[i][j][r] + bval);
          } else {
            uint2 o;
            o.x = pkbf(acc[i][j][0] + bval, acc[i][j][1] + bval);
            o.y = pkbf(acc[i][j][2] + bval, acc[i][j][3] + bval);
            *(uint2*)&((u16*)out3)[(((size_t)hh * 64 + f) << 12) + rowb] = o;
          }
        }
      } else {
#pragma unroll
        for (int i = 0; i < WR; i++) {
          const int rowb = row0 + wm + i * 16 + quad * 4;
#pragma unroll
          for (int r = 0; r < 4; r++) {
            float vv = acc[i][j][r] + bval;
            size_t idx = (size_t)(rowb + r) * N + col;
            if (MODE == 1) {
              ((u16*)out)[idx] = f2bf(fmaxf(vv, 0.f));
            } else if (MODE == 2) {
              ((float*)out)[idx] = vv + loadf(resid, idx, isf);
            } else if (MODE == 3) {
              float o = vv + ((const float*)resid)[idx];
              if (isf) ((float*)out)[idx] = o;
              else     ((u16*)out)[idx]   = f2bf(o);
            }
          }
        }
      }
    }
  }
}

// ---------------------------------------------------------------------------
// Flash attention, split-K, hybrid-MFMA transposed form. R13: 128-q tiles,
// 64-token compute halves, JIT staging, 64-VGPR budget (launch_bounds(512,8)).
// Block = (combo=h*2+b, qt128, ci): 128 q (8 waves x 16, q = lane&15 column)
// vs k-chunk <=1024 (<=8 steps of 128). 4 blocks/CU = 32 waves resident.
// QK^T: S^T = K·Q^T via 16x16x32 (K A-frags contiguous 16B -> ds_read_b128).
// P^T stays in registers, feeds O^T = V^T·P^T via 16x16x16; V staged
// PERMUTED (c' = quad*32 + kt*4 + j) so PV A-frags are b128 reads.
// Each 128-token LDS step is computed as two 64-token halves (sc[4] = 16
// VGPR live, not sc[8] = 32) with per-half max/defer-rescale/exp/PV.
// Tiles with nc==1 (qt<=7) normalize in-kernel and write z directly.
// ---------------------------------------------------------------------------
__global__ __launch_bounds__(512, 8) void attn_part(
    const u16* __restrict__ qh, const u16* __restrict__ kh,
    const u16* __restrict__ vT, u16* __restrict__ Opart,
    float* __restrict__ stats, u16* __restrict__ z) {
  const int combo = blockIdx.x;      // h*2 + b
  const int qt = blockIdx.y;         // 0..15 (128-row q-tiles)
  const int ci = blockIdx.z;         // 0..1 (1024-chunks)
  const int q0 = qt << 7;
  const int nc = (q0 + 128 + 1023) >> 10;
  if (ci >= nc) return;
  const int k_lo = ci << 10;
  const int k_hi = min(k_lo + 1024, q0 + 128);
  const int nsteps = (k_hi - k_lo + 127) >> 7;

  __shared__ u16 kS[128 * 72];       // K tile [tok][64+8 pad]; reused as O bounce
  __shared__ u16 vS[64 * 136];       // V^T tile [f][128 permuted + 8 pad]
  const int tid = threadIdx.x, L = tid & 63, w = tid >> 6;   // w 0..7
  const int m = L & 15, quad = L >> 4;
  const int h = combo >> 1, b = combo & 1;
  const size_t tb = (size_t)b * 2048;
  const size_t hbase = (size_t)h * 4096;
  const int qg = q0 + w * 16 + m;    // this lane's global q (column)

  // Q as 16x16x32 B-frags: lane n=q, k=feat quad*8+j (two 32-feat chunks)
  bf16x8 qb0, qb1;
  {
    const u16* qp = qh + ((hbase + tb + (size_t)qg) << 6) + quad * 8;
    qb0 = *(const bf16x8*)qp;
    qb1 = *(const bf16x8*)(qp + 32);
  }

  f32x4 zero4 = {0.f, 0.f, 0.f, 0.f};
  f32x4 O[4];                        // O^T: lane q, f = ft*16 + quad*4 + r
#pragma unroll
  for (int ft = 0; ft < 4; ft++) O[ft] = zero4;
  float mrow = -30000.f, lrow = 0.f;

  // staging: 512 thr, K tile 128x64 (1024 int4, 2 per thread),
  // V tile 64x128 (1024 int4, 2 per thread)
  const int krow[2] = { (0*512+tid) >> 3, (1*512+tid) >> 3 };
  const int kc = tid & 7;
  const int vf[2] = { (0*512+tid) >> 4, (1*512+tid) >> 4 };
  const int vc = tid & 15;
  // permuted V column bases for the two 4-elem halves of each int4
  const int vq = (vc & 1) << 1;             // quad base 2*(vc&1)
  const int vk4 = (vc >> 1) << 2;           // kt*4
  const int vc0 = (vq << 5) + vk4;          // quad*32 + kt*4
  const int vc1 = ((vq + 1) << 5) + vk4;

  for (int j = 0; j < nsteps; j++) {
    const int k0 = k_lo + (j << 7);
    // JIT load this step's K/V (issued before the barrier so the HBM
    // latency overlaps the barrier wait; regs are short-lived)
    int4 kr[2], vr[2];
#pragma unroll
    for (int i = 0; i < 2; i++) {
      kr[i] = *(const int4*)(kh + ((hbase + tb + k0 + krow[i]) << 6) + kc * 8);
      vr[i] = *(const int4*)(vT + (((size_t)h * 64 + vf[i]) << 12) + tb + k0 + vc * 8);
    }
    __syncthreads();                 // prev-step LDS consumers done
#pragma unroll
    for (int i = 0; i < 2; i++) {
      *(int4*)&kS[krow[i] * 72 + kc * 8] = kr[i];
      union { int4 v; s16x4 hh[2]; } tv; tv.v = vr[i];
      *(s16x4*)&vS[vf[i] * 136 + vc0] = tv.hh[0];
      *(s16x4*)&vS[vf[i] * 136 + vc1] = tv.hh[1];
    }
    __syncthreads();

    // two 64-token halves: sc[4] live instead of sc[8]
#pragma unroll
    for (int hs = 0; hs < 2; hs++) {
      const int kbase = k0 + hs * 64;
      f32x4 sc[4];
#pragma unroll
      for (int kt4 = 0; kt4 < 4; kt4++) {
        const int kt = hs * 4 + kt4;
        const u16* kp = &kS[(kt * 16 + m) * 72 + quad * 8];
        bf16x8 ka0 = *(const bf16x8*)kp;
        bf16x8 ka1 = *(const bf16x8*)(kp + 32);
        f32x4 t = zero4;
        t = __builtin_amdgcn_mfma_f32_16x16x32_bf16(ka0, qb0, t, 0, 0, 0);
        t = __builtin_amdgcn_mfma_f32_16x16x32_bf16(ka1, qb1, t, 0, 0, 0);
        sc[kt4] = t;
      }
      if (kbase + 64 > q0) {   // touches diagonal region: causal mask
#pragma unroll
        for (int kt4 = 0; kt4 < 4; kt4++)
#pragma unroll
          for (int r = 0; r < 4; r++) {
            int ktok = kbase + kt4 * 16 + quad * 4 + r;
            if (ktok > qg) sc[kt4][r] = -30000.f;
          }
      }
      // per-lane max over 16 regs + 2 shuffles (q fixed per lane)
      float mx = sc[0][0];
#pragma unroll
      for (int kt4 = 0; kt4 < 4; kt4++)
#pragma unroll
        for (int r = 0; r < 4; r++) mx = fmaxf(mx, sc[kt4][r]);
      mx = fmaxf(mx, __shfl_xor(mx, 16, 64));
      mx = fmaxf(mx, __shfl_xor(mx, 32, 64));
      // defer-max (T13): only rescale when max grew by > 8 (exp2 domain)
      if (!__all(mx <= mrow + 8.f)) {
        float mnew = fmaxf(mrow, mx);
        float alpha = __builtin_amdgcn_exp2f(mrow - mnew);
        lrow *= alpha;
#pragma unroll
        for (int ft = 0; ft < 4; ft++) O[ft] *= alpha;
        mrow = mnew;
      }
      // P^T = exp2(S^T - m): pack to bf16 B-frags; accumulate l inline
      s16x4 pb[4];
      float sum = 0.f;
#pragma unroll
      for (int kt4 = 0; kt4 < 4; kt4++) {
        float e0 = __builtin_amdgcn_exp2f(sc[kt4][0] - mrow);
        float e1 = __builtin_amdgcn_exp2f(sc[kt4][1] - mrow);
        float e2 = __builtin_amdgcn_exp2f(sc[kt4][2] - mrow);
        float e3 = __builtin_amdgcn_exp2f(sc[kt4][3] - mrow);
        sum += (e0 + e1) + (e2 + e3);
        union { uint2 u; s16x4 hh; } pu;
        pu.u.x = pkbf(e0, e1);
        pu.u.y = pkbf(e2, e3);
        pb[kt4] = pu.hh;
      }
      sum += __shfl_xor(sum, 16, 64);
      sum += __shfl_xor(sum, 32, 64);
      lrow += sum;
      // O^T += V^T·P^T via 16x16x16 over this half's k-slots
      // (pr = hs*2 + p2; 8 contiguous u16 = 2 A-frags per b128 read)
#pragma unroll
      for (int ft = 0; ft < 4; ft++) {
        const u16* vp = &vS[(ft * 16 + m) * 136 + quad * 32 + hs * 16];
#pragma unroll
        for (int p2 = 0; p2 < 2; p2++) {
          union { bf16x8 v; s16x4 hh[2]; } u;
          u.v = *(const bf16x8*)(vp + p2 * 8);
          O[ft] = mfma16(u.hh[0], pb[2 * p2],     O[ft]);
          O[ft] = mfma16(u.hh[1], pb[2 * p2 + 1], O[ft]);
        }
      }
    }
  }

  // nc==1: normalize in-kernel (diagonal guarantees lrow > 0)
  if (nc == 1) {
    float inv = 1.f / lrow;
#pragma unroll
    for (int ft = 0; ft < 4; ft++) O[ft] *= inv;
  }

  // O^T -> LDS bounce (kS reused, 128 rows x 64f) -> coalesced global stores
  __syncthreads();
#pragma unroll
  for (int ft = 0; ft < 4; ft++) {
    union { uint2 u; s16x4 hh; } o4;
    o4.u.x = pkbf(O[ft][0], O[ft][1]);
    o4.u.y = pkbf(O[ft][2], O[ft][3]);
    *(s16x4*)&kS[(w * 16 + m) * 72 + ft * 16 + quad * 4] = o4.hh;
  }
  __syncthreads();
  if (nc == 1) {
    // direct z write: [tok][1024] layout, this head's 64-col stripe
    u16* zp = z + ((tb + (size_t)q0) << 10) + h * 64;
#pragma unroll
    for (int it = 0; it < 2; it++) {
      int idx = it * 512 + tid;
      int row = idx >> 3, c = idx & 7;
      *(int4*)&zp[((size_t)row << 10) + c * 8] = *(const int4*)&kS[row * 72 + c * 8];
    }
  } else {
    const int slot = (combo * 16 + qt) * 2 + ci;
    u16* op = Opart + ((size_t)slot << 13);
#pragma unroll
    for (int it = 0; it < 2; it++) {
      int idx = it * 512 + tid;
      int row = idx >> 3, c = idx & 7;
      *(int4*)&op[row * 64 + c * 8] = *(const int4*)&kS[row * 72 + c * 8];
    }
    if (quad == 0) {
      stats[slot * 256 + w * 16 + m]       = mrow;
      stats[slot * 256 + 128 + w * 16 + m] = lrow;
    }
  }
}

// merge partials -> z [t][1024]; only qt>=8 tiles (nc==2) reach here. 512 thr.
__global__ __launch_bounds__(512) void attn_merge(
    const u16* __restrict__ Opart, const float* __restrict__ stats,
    u16* __restrict__ z) {
  const int combo = blockIdx.x, qt = 8 + blockIdx.y;
  const int h = combo >> 1, b = combo & 1;
  const int q0 = qt << 7;
  const int tid = threadIdx.x;
  const int t = tid >> 2, f0 = (tid & 3) << 4;   // t 0..127
  const int slot0 = (combo * 16 + qt) * 2;
  float M = fmaxf(stats[slot0 * 256 + t], stats[(slot0 + 1) * 256 + t]);
  float acc[16];
#pragma unroll
  for (int e = 0; e < 16; e++) acc[e] = 0.f;
  float ltot = 0.f;
#pragma unroll
  for (int ci = 0; ci < 2; ci++) {
    float mi = stats[(slot0 + ci) * 256 + t];
    float li = stats[(slot0 + ci) * 256 + 128 + t];
    float wgt = exp2f(mi - M);
    ltot += wgt * li;
    const u16* op = Opart + (((size_t)(slot0 + ci)) << 13) + t * 64 + f0;
    union { int4 v; u16 u[8]; } a0, a1;
    a0.v = *(const int4*)op;
    a1.v = *(const int4*)(op + 8);
#pragma unroll
    for (int e = 0; e < 8; e++) {
      acc[e]     += wgt * bf2f(a0.u[e]);
      acc[8 + e] += wgt * bf2f(a1.u[e]);
    }
  }
  float inv = 1.f / ltot;
  union { int4 v; u16 u[8]; } o0, o1;
#pragma unroll
  for (int e = 0; e < 8; e++) {
    o0.u[e] = f2bf(acc[e] * inv);
    o1.u[e] = f2bf(acc[8 + e] * inv);
  }
  size_t tok = (size_t)b * 2048 + q0 + t;
  *(int4*)&z[tok * 1024 + h * 64 + f0]     = o0.v;
  *(int4*)&z[tok * 1024 + h * 64 + f0 + 8] = o1.v;
}

// ---------------------------------------------------------------------------
extern "C" void kernel_launch(void* const* d_in, const int* in_sizes, int n_in,
                              void* d_out, int out_size, void* d_ws, size_t ws_size,
                              hipStream_t stream) {
  (void)in_sizes; (void)n_in; (void)out_size; (void)ws_size;
  const void* resid_pre = d_in[0];
  const void* ln1_w = d_in[1];
  const void* ln1_b = d_in[2];
  const void* W_Q   = d_in[3];
  const void* b_Q   = d_in[4];
  const void* W_K   = d_in[5];
  const void* b_K   = d_in[6];
  const void* W_V   = d_in[7];
  const void* b_V   = d_in[8];
  const void* W_O   = d_in[9];
  const void* b_O   = d_in[10];
  const void* ln2_w = d_in[11];
  const void* ln2_b = d_in[12];
  const void* W_in  = d_in[13];
  const void* b_in  = d_in[14];
  const void* W_out = d_in[15];
  const void* b_out = d_in[16];

  char* p = (char*)d_ws;
  auto alloc = [&](size_t bytes) {
    char* r = p; p += (bytes + 255) & ~(size_t)255; return (void*)r;
  };
  int*   flag      = (int*)  alloc(256);
  u16*   WqkvT     = (u16*)  alloc(3072ull * 1024 * 2);
  u16*   WoT       = (u16*)  alloc(1024ull * 1024 * 2);
  u16*   WinT      = (u16*)  alloc(4096ull * 1024 * 2);
  u16*   WoutT     = (u16*)  alloc(1024ull * 4096 * 2);
  float* biases    = (float*)alloc(9216 * 4);
  u16*   xn        = (u16*)  alloc(4096ull * 1024 * 2);  // reused as z
  u16*   q_hm      = (u16*)  alloc(16ull * 4096 * 64 * 2);
  u16*   k_hm      = (u16*)  alloc(16ull * 4096 * 64 * 2);
  u16*   vTws      = (u16*)  alloc(16ull * 64 * 4096 * 2);
  float* resid_mid = (float*)alloc(4096ull * 1024 * 4);
  u16*   h2        = (u16*)  alloc(4096ull * 1024 * 2);  // attn stats before ln2
  u16*   act       = (u16*)  alloc(4096ull * 4096 * 2);  // attn partials before MLP
  u16*   z = xn;
  u16*   Opart = act;              // 1024 slots x 16 KB = 16 MB (< 32 MB)
  float* stats = (float*)h2;       // 1024 slots x 256 fp32 = 1 MB < 8 MB

  detect_dtype<<<1, 256, 0, stream>>>((const unsigned int*)resid_pre, flag);

  pack_qkv_tiled<<<dim3(16, 48), 256, 0, stream>>>(flag, W_Q, W_K, W_V, WqkvT);
  transpose_tiled<<<dim3(16, 16), 256, 0, stream>>>(flag, W_O,   WoT,   1024, 1024);
  transpose_tiled<<<dim3(64, 16), 256, 0, stream>>>(flag, W_in,  WinT,  1024, 4096);
  transpose_tiled<<<dim3(16, 64), 256, 0, stream>>>(flag, W_out, WoutT, 4096, 1024);
  pack_biases<<<36, 256, 0, stream>>>(flag, b_Q, b_K, b_V, b_O, b_in, b_out, biases);

  ln_fwd<0><<<4096, 256, 0, stream>>>(flag, resid_pre, ln1_w, ln1_b, xn);
  // qkv -> head-major q/k + transposed v. grid: 8 XCD x SH=4 rows x 24 cols
  gemm_bt<4, 128, 1><<<768, 256, 0, stream>>>(
      flag, xn, WqkvT, biases, nullptr, q_hm, k_hm, vTws, 4096, 3072, 1024, 2);
  // split-K causal flash attention (128-q tiles, 1024-chunks) -> z
  attn_part<<<dim3(32, 16, 2), 512, 0, stream>>>(q_hm, k_hm, vTws, Opart, stats, z);
  attn_merge<<<dim3(32, 8), 512, 0, stream>>>(Opart, stats, z);
  // resid_mid = resid_pre + z @ W_O + b_O   (fp32). 8 XCD x SH=8 x 8 cols,
  // in-block split-K (512 thr)
  gemm_bt<2, 64, 2><<<512, 512, 0, stream>>>(
      flag, z, WoT, biases + 3072, resid_pre, resid_mid, nullptr, nullptr, 4096, 1024, 1024, 3);
  ln_fwd<1><<<4096, 256, 0, stream>>>(flag, resid_mid, ln2_w, ln2_b, h2);
  // act = relu(h2 @ W_in + b_in). 8 XCD x SH=4 x 32 cols
  gemm_bt<1, 128, 1><<<1024, 256, 0, stream>>>(
      flag, h2, WinT, biases + 4096, nullptr, act, nullptr, nullptr, 4096, 4096, 1024, 2);
  // out = resid_mid + act @ W_out + b_out. 8 XCD x SH=8 x 8 cols,
  // in-block split-K (512 thr)
  gemm_bt<3, 64, 2><<<512, 512, 0, stream>>>(
      flag, act, WoutT, biases + 8192, resid_mid, d_out, nullptr, nullptr, 4096, 1024, 4096, 3);
}

// Round 6
// 414.047 us; speedup vs baseline: 1.0959x; 1.0596x over previous
//
#include <hip/hip_runtime.h>
#include <stdint.h>

// ---------------------------------------------------------------------------
// TransformerBlock on MI355X (gfx950). Runtime dtype detection (fp32 vs bf16
// inputs), bf16-MFMA internal compute, fp32 accumulation + fp32 residual path.
// B=2 S=2048 D=1024 H=16 K=64 MLP=4096; tokens M = 4096.
// R8: attention hybrid MFMA shapes — QK^T via 16x16x32 (b128 K reads),
// PV via 16x16x16 with permuted V staging (b128 V reads).
// R9: MODE 2/3 gemms get in-block split-K (512 thr, padded-LDS combine).
// R10/R11: attn chunk 1024, direct-z for single-chunk tiles, defer-max.
// R12/R13 LESSON: gfx950 unified VGPR/AGPR file — launch_bounds(512,N) caps
// TOTAL regs/wave at 512/N per SIMD, allocator splits arch/acc halves.
// (512,8)->64 cap vs ~96 demand = ~32 spilled regs/lane -> 135-140 MB of
// scratch HBM traffic (WRITE_SIZE 148-157 MB vs 13 MB model); attn_part has
// been spill-bound since R9.
// R14: correct tier: launch_bounds(512,4) -> 128-reg cap >= 96 demand,
// ZERO spill, 4 waves/SIMD = 2 blocks/CU = 16 waves/CU. Everything else
// identical to R13 (128-q tiles, 64-token halves, JIT staging).
// ---------------------------------------------------------------------------

typedef unsigned short u16;
typedef __bf16 bf16x8 __attribute__((ext_vector_type(8)));
typedef __bf16 bf16x4 __attribute__((ext_vector_type(4)));
typedef __bf16 bf16x2 __attribute__((ext_vector_type(2)));
typedef short  s16x4  __attribute__((ext_vector_type(4)));
typedef float  f32x4  __attribute__((ext_vector_type(4)));

#define QSCALE 0.18033688011112042f   // (1/sqrt(64)) * log2(e): softmax via exp2

__device__ __forceinline__ float bf2f(unsigned int u) {
  union { unsigned int u; float f; } v; v.u = u << 16; return v.f;
}
__device__ __forceinline__ u16 f2bf(float f) {
  union { float f; unsigned int u; } v; v.f = f;
  unsigned int r = v.u + 0x7FFFu + ((v.u >> 16) & 1u);   // RNE
  return (u16)(r >> 16);
}
__device__ __forceinline__ unsigned pkbf(float lo, float hi) {
#if __has_builtin(__builtin_amdgcn_cvt_pk_bf16_f32)
  bf16x2 t = __builtin_amdgcn_cvt_pk_bf16_f32(lo, hi);
  return __builtin_bit_cast(unsigned, t);
#else
  return (unsigned)f2bf(lo) | ((unsigned)f2bf(hi) << 16);
#endif
}
__device__ __forceinline__ float loadf(const void* p, size_t i, int isf) {
  return isf ? ((const float*)p)[i] : bf2f(((const u16*)p)[i]);
}

// 16x16x16 bf16 MFMA wrapper
__device__ __forceinline__ f32x4 mfma16(s16x4 a, s16x4 b, f32x4 c) {
#if __has_builtin(__builtin_amdgcn_mfma_f32_16x16x16_bf16)
  return __builtin_amdgcn_mfma_f32_16x16x16_bf16(
      __builtin_bit_cast(bf16x4, a), __builtin_bit_cast(bf16x4, b), c, 0, 0, 0);
#else
  return __builtin_amdgcn_mfma_f32_16x16x16bf16_1k(a, b, c, 0, 0, 0);
#endif
}

// ---------------------------------------------------------------------------
__global__ __launch_bounds__(256) void detect_dtype(
    const unsigned int* __restrict__ x, int* __restrict__ flag) {
  __shared__ int cnt;
  if (threadIdx.x == 0) cnt = 0;
  __syncthreads();
  int c = 0;
  for (int i = threadIdx.x; i < 512; i += 256) {
    unsigned int e = (x[i] >> 23) & 0xFFu;
    if (e >= 97u && e <= 157u) c++;
  }
  atomicAdd(&cnt, c);
  __syncthreads();
  if (threadIdx.x == 0) *flag = (cnt > 384) ? 1 : 0;
}

// ---------------------------------------------------------------------------
// Tiled transposes: 64x64 tiles through LDS (stride-65 pad -> 2-way = free).
// ---------------------------------------------------------------------------
__global__ __launch_bounds__(256) void pack_qkv_tiled(
    const int* __restrict__ flagp,
    const void* __restrict__ Wq, const void* __restrict__ Wk, const void* __restrict__ Wv,
    u16* __restrict__ WT) {
  __shared__ float t[64][65];
  const int isf = *flagp;
  const int tid = threadIdx.x;
  const int mh = blockIdx.y;            // mat*16 + h
  const int mat = mh >> 4, h = mh & 15;
  const int d0 = blockIdx.x << 6;       // d-tile
  const void* src = (mat == 0) ? Wq : (mat == 1) ? Wk : Wv;
  const float scale = (mat == 0) ? QSCALE : 1.f;
  const int lane = tid & 63, rr = tid >> 6;
  const size_t sbase = ((size_t)h << 16) + lane;
#pragma unroll
  for (int i = 0; i < 16; i++) {
    int d = i * 4 + rr;
    t[d][lane] = loadf(src, sbase + (size_t)(d0 + d) * 64, isf) * scale;
  }
  __syncthreads();
#pragma unroll
  for (int i = 0; i < 16; i++) {
    int k = i * 4 + rr;
    WT[((size_t)((mat << 10) + (h << 6) + k) << 10) + d0 + lane] = f2bf(t[lane][k]);
  }
}

__global__ __launch_bounds__(256) void transpose_tiled(
    const int* __restrict__ flagp, const void* __restrict__ src,
    u16* __restrict__ dst, int R, int C) {
  __shared__ float t[64][65];
  const int isf = *flagp;
  const int tid = threadIdx.x;
  const int c0 = blockIdx.x << 6, r0 = blockIdx.y << 6;
  const int lane = tid & 63, rr = tid >> 6;
#pragma unroll
  for (int i = 0; i < 16; i++) {
    int r = i * 4 + rr;
    t[r][lane] = loadf(src, (size_t)(r0 + r) * C + c0 + lane, isf);
  }
  __syncthreads();
#pragma unroll
  for (int i = 0; i < 16; i++) {
    int c = i * 4 + rr;
    dst[(size_t)(c0 + c) * R + r0 + lane] = f2bf(t[lane][c]);
  }
}

__global__ __launch_bounds__(256) void pack_biases(
    const int* __restrict__ flagp,
    const void* bq, const void* bk, const void* bv,
    const void* bO, const void* bin, const void* bout,
    float* __restrict__ out) {
  const int isf = *flagp;
  int i = blockIdx.x * 256 + threadIdx.x;
  float v;
  if (i < 1024)      v = loadf(bq,   i,        isf) * QSCALE;
  else if (i < 2048) v = loadf(bk,   i - 1024, isf);
  else if (i < 3072) v = loadf(bv,   i - 2048, isf);
  else if (i < 4096) v = loadf(bO,   i - 3072, isf);
  else if (i < 8192) v = loadf(bin,  i - 4096, isf);
  else               v = loadf(bout, i - 8192, isf);
  out[i] = v;
}

// ---------------------------------------------------------------------------
template<int SRC>
__global__ __launch_bounds__(256) void ln_fwd(
    const int* __restrict__ flagp, const void* __restrict__ xin,
    const void* __restrict__ w, const void* __restrict__ b,
    u16* __restrict__ out) {
  const int isf = *flagp;
  const int row = blockIdx.x, tid = threadIdx.x;
  const int col = tid << 2;
  const size_t base = ((size_t)row << 10) + col;
  float v[4];
#pragma unroll
  for (int i = 0; i < 4; i++)
    v[i] = (SRC == 1) ? ((const float*)xin)[base + i] : loadf(xin, base + i, isf);
  float s  = v[0] + v[1] + v[2] + v[3];
  float ss = v[0]*v[0] + v[1]*v[1] + v[2]*v[2] + v[3]*v[3];
#pragma unroll
  for (int mk = 32; mk >= 1; mk >>= 1) {
    s  += __shfl_xor(s,  mk, 64);
    ss += __shfl_xor(ss, mk, 64);
  }
  __shared__ float red[8];
  if ((tid & 63) == 0) { red[tid >> 6] = s; red[4 + (tid >> 6)] = ss; }
  __syncthreads();
  float S  = red[0] + red[1] + red[2] + red[3];
  float SS = red[4] + red[5] + red[6] + red[7];
  float mean = S * (1.f / 1024.f);
  float var  = SS * (1.f / 1024.f) - mean * mean;
  float rstd = rsqrtf(var + 1e-5f);
  u16 e[4];
#pragma unroll
  for (int i = 0; i < 4; i++) {
    float wv = loadf(w, col + i, isf);
    float bv = loadf(b, col + i, isf);
    e[i] = f2bf((v[i] - mean) * rstd * wv + bv);
  }
  uint2 o;
  o.x = (unsigned)e[0] | ((unsigned)e[1] << 16);
  o.y = (unsigned)e[2] | ((unsigned)e[3] << 16);
  *(uint2*)(out + base) = o;
}

// ---------------------------------------------------------------------------
// GEMM C[M,N] = A[M,K] @ BT[N,K]^T + bias. KW*256 threads.
// TM=128: wave tile 64x64 (acc 4x4). TM=64: wave tile 32x64 (acc 2x4).
// KW=2: in-block split-K (wave-group per K half, padded-LDS combine).
// Staging: int4 register prefetch one compute phase ahead.
// XCD-swizzled 1-D grid.
// MODE 1: relu+bf16; 2: +flagged resid -> fp32; 3: +fp32 resid -> flagged out
// MODE 4: QKV epilogue -> q_hm[h][t][64], k_hm, vT[h][f][4096]
// ---------------------------------------------------------------------------
template<int MODE, int TM, int KW>
__global__ __launch_bounds__(KW * 256) void gemm_bt(
    const int* __restrict__ flagp,
    const u16* __restrict__ A, const u16* __restrict__ BT,
    const float* __restrict__ bias, const void* __restrict__ resid,
    void* __restrict__ out, void* __restrict__ out2, void* __restrict__ out3,
    int M, int N, int K, int SHL) {
  constexpr int WR = TM / 32;          // row-frags per wave
  constexpr int ASZ = TM * 32;         // per-group LDS elements (u16)
  constexpr int BSZ = 128 * 32;
  constexpr int STAGE_B = KW * (ASZ + BSZ) * 2;
  constexpr int RED_B = (KW > 1) ? TM * 132 * 4 : 1;   // padded fp32 combine
  constexpr int SMEM_B = STAGE_B > RED_B ? STAGE_B : RED_B;
  __shared__ __align__(16) char smem[SMEM_B];
  u16* as = (u16*)smem;
  u16* bs = (u16*)smem + KW * ASZ;

  int isf = 0;
  if (MODE == 2 || MODE == 3) isf = *flagp;
  const int Lb = blockIdx.x;
  const int xcd = Lb & 7, sidx = Lb >> 3;
  const int SH = 1 << SHL;
  const int by = xcd * SH + (sidx & (SH - 1));
  const int bx = sidx >> SHL;
  const int tid = threadIdx.x;
  const int L = tid & 63, w = tid >> 6;
  const int g = w >> 2, wl = w & 3;    // wave-group (K-split), wave-in-group
  const int wm = (wl >> 1) * (TM >> 1), wn = (wl & 1) << 6;
  const int row0 = by * TM, col0 = bx << 7;
  const int m = L & 15, quad = L >> 4;

  f32x4 zero4 = {0.f, 0.f, 0.f, 0.f};
  f32x4 acc[WR][4];
#pragma unroll
  for (int i = 0; i < WR; i++)
#pragma unroll
    for (int j = 0; j < 4; j++) acc[i][j] = zero4;

  const int KSEG = K / KW;
  const int tl = tid & 255;            // staging id within group
  const int tm = tl >> 2;
  const int tk = (tl & 3) << 3;
  const u16* Ag  = A  + (size_t)(row0 + tm) * K + g * KSEG + tk;
  const u16* Ag2 = Ag + (size_t)64 * K;          // TM==128 only
  const u16* Bg  = BT + (size_t)(col0 + tm) * K + g * KSEG + tk;
  const u16* Bg2 = Bg + (size_t)64 * K;
  u16* asg  = as + g * ASZ;
  u16* bsg  = bs + g * BSZ;
  u16* asl  = asg + tl * 8;
  u16* asl2 = asg + 2048 + tl * 8;
  u16* bsl  = bsg + tl * 8;
  u16* bsl2 = bsg + 2048 + tl * 8;

  const int aoff = (wm + m) * 32 + quad * 8;
  const int boff = (wn + m) * 32 + quad * 8;

  int4 ar0, ar1, br0, br1;
  ar0 = *(const int4*)Ag;
  if (TM == 128) ar1 = *(const int4*)Ag2;
  br0 = *(const int4*)Bg;
  br1 = *(const int4*)Bg2;

  for (int kk = 0; kk < KSEG; kk += 32) {
    __syncthreads();                    // LDS consumers of prev step done
    *(int4*)asl = ar0;
    if (TM == 128) *(int4*)asl2 = ar1;
    *(int4*)bsl = br0;
    *(int4*)bsl2 = br1;
    __syncthreads();
    if (kk + 32 < KSEG) {               // prefetch next step into registers
      ar0 = *(const int4*)(Ag + kk + 32);
      if (TM == 128) ar1 = *(const int4*)(Ag2 + kk + 32);
      br0 = *(const int4*)(Bg + kk + 32);
      br1 = *(const int4*)(Bg2 + kk + 32);
    }
    bf16x8 af[WR], bfr[4];
#pragma unroll
    for (int i = 0; i < WR; i++) af[i]  = *(const bf16x8*)&asg[aoff + i * 512];
#pragma unroll
    for (int j = 0; j < 4; j++) bfr[j] = *(const bf16x8*)&bsg[boff + j * 512];
#pragma unroll
    for (int i = 0; i < WR; i++)
#pragma unroll
      for (int j = 0; j < 4; j++)
        acc[i][j] = __builtin_amdgcn_mfma_f32_16x16x32_bf16(af[i], bfr[j], acc[i][j], 0, 0, 0);
  }

  if (KW > 1) {
    // combine group 1's accumulators into group 0 through padded LDS.
    __syncthreads();                    // staging LDS dead from here
    float* red = (float*)smem;
    if (g == 1) {
#pragma unroll
      for (int i = 0; i < WR; i++)
#pragma unroll
        for (int j = 0; j < 4; j++)
#pragma unroll
          for (int r = 0; r < 4; r++)
            red[(wm + i * 16 + quad * 4 + r) * 132 + wn + j * 16 + m] = acc[i][j][r];
    }
    __syncthreads();
    if (g == 0) {
#pragma unroll
      for (int i = 0; i < WR; i++)
#pragma unroll
        for (int j = 0; j < 4; j++)
#pragma unroll
          for (int r = 0; r < 4; r++)
            acc[i][j][r] += red[(wm + i * 16 + quad * 4 + r) * 132 + wn + j * 16 + m];
    }
  }

  if (g == 0) {
#pragma unroll
    for (int j = 0; j < 4; j++) {
      const int col = col0 + wn + j * 16 + m;
      const float bval = bias[col];
      if (MODE == 4) {
        const int sel = col >> 10;
        const int hh  = (col >> 6) & 15;
        const int f   = col & 63;
#pragma unroll
        for (int i = 0; i < WR; i++) {
          const int rowb = row0 + wm + i * 16 + quad * 4;
          if (sel < 2) {
            u16* dst = (u16*)(sel ? out2 : out);
#pragma unroll
            for (int r = 0; r < 4; r++)
              dst[((((size_t)hh << 12) + rowb + r) << 6) + f] = f2bf(acc[i][j][r] + bval);
          } else {
            uint2 o;
            o.x = pkbf(acc[i][j][0] + bval, acc[i][j][1] + bval);
            o.y = pkbf(acc[i][j][2] + bval, acc[i][j][3] + bval);
            *(uint2*)&((u16*)out3)[(((size_t)hh * 64 + f) << 12) + rowb] = o;
          }
        }
      } else {
#pragma unroll
        for (int i = 0; i < WR; i++) {
          const int rowb = row0 + wm + i * 16 + quad * 4;
#pragma unroll
          for (int r = 0; r < 4; r++) {
            float vv = acc[i][j][r] + bval;
            size_t idx = (size_t)(rowb + r) * N + col;
            if (MODE == 1) {
              ((u16*)out)[idx] = f2bf(fmaxf(vv, 0.f));
            } else if (MODE == 2) {
              ((float*)out)[idx] = vv + loadf(resid, idx, isf);
            } else if (MODE == 3) {
              float o = vv + ((const float*)resid)[idx];
              if (isf) ((float*)out)[idx] = o;
              else     ((u16*)out)[idx]   = f2bf(o);
            }
          }
        }
      }
    }
  }
}

// ---------------------------------------------------------------------------
// Flash attention, split-K, hybrid-MFMA transposed form. R14: 128-q tiles,
// 64-token compute halves, JIT staging, launch_bounds(512,4) -> 128-reg cap
// (gfx950 unified VGPR+AGPR) >= ~96 demand: ZERO spill, 2 blocks/CU.
// Block = (combo=h*2+b, qt128, ci): 128 q (8 waves x 16, q = lane&15 column)
// vs k-chunk <=1024 (<=8 steps of 128).
// QK^T: S^T = K·Q^T via 16x16x32 (K A-frags contiguous 16B -> ds_read_b128).
// P^T stays in registers, feeds O^T = V^T·P^T via 16x16x16; V staged
// PERMUTED (c' = quad*32 + kt*4 + j) so PV A-frags are b128 reads.
// Each 128-token LDS step is computed as two 64-token halves (sc[4] live).
// Tiles with nc==1 (qt<=7) normalize in-kernel and write z directly.
// ---------------------------------------------------------------------------
__global__ __launch_bounds__(512, 4) void attn_part(
    const u16* __restrict__ qh, const u16* __restrict__ kh,
    const u16* __restrict__ vT, u16* __restrict__ Opart,
    float* __restrict__ stats, u16* __restrict__ z) {
  const int combo = blockIdx.x;      // h*2 + b
  const int qt = blockIdx.y;         // 0..15 (128-row q-tiles)
  const int ci = blockIdx.z;         // 0..1 (1024-chunks)
  const int q0 = qt << 7;
  const int nc = (q0 + 128 + 1023) >> 10;
  if (ci >= nc) return;
  const int k_lo = ci << 10;
  const int k_hi = min(k_lo + 1024, q0 + 128);
  const int nsteps = (k_hi - k_lo + 127) >> 7;

  __shared__ u16 kS[128 * 72];       // K tile [tok][64+8 pad]; reused as O bounce
  __shared__ u16 vS[64 * 136];       // V^T tile [f][128 permuted + 8 pad]
  const int tid = threadIdx.x, L = tid & 63, w = tid >> 6;   // w 0..7
  const int m = L & 15, quad = L >> 4;
  const int h = combo >> 1, b = combo & 1;
  const size_t tb = (size_t)b * 2048;
  const size_t hbase = (size_t)h * 4096;
  const int qg = q0 + w * 16 + m;    // this lane's global q (column)

  // Q as 16x16x32 B-frags: lane n=q, k=feat quad*8+j (two 32-feat chunks)
  bf16x8 qb0, qb1;
  {
    const u16* qp = qh + ((hbase + tb + (size_t)qg) << 6) + quad * 8;
    qb0 = *(const bf16x8*)qp;
    qb1 = *(const bf16x8*)(qp + 32);
  }

  f32x4 zero4 = {0.f, 0.f, 0.f, 0.f};
  f32x4 O[4];                        // O^T: lane q, f = ft*16 + quad*4 + r
#pragma unroll
  for (int ft = 0; ft < 4; ft++) O[ft] = zero4;
  float mrow = -30000.f, lrow = 0.f;

  // staging: 512 thr, K tile 128x64 (1024 int4, 2 per thread),
  // V tile 64x128 (1024 int4, 2 per thread)
  const int krow[2] = { (0*512+tid) >> 3, (1*512+tid) >> 3 };
  const int kc = tid & 7;
  const int vf[2] = { (0*512+tid) >> 4, (1*512+tid) >> 4 };
  const int vc = tid & 15;
  // permuted V column bases for the two 4-elem halves of each int4
  const int vq = (vc & 1) << 1;             // quad base 2*(vc&1)
  const int vk4 = (vc >> 1) << 2;           // kt*4
  const int vc0 = (vq << 5) + vk4;          // quad*32 + kt*4
  const int vc1 = ((vq + 1) << 5) + vk4;

  for (int j = 0; j < nsteps; j++) {
    const int k0 = k_lo + (j << 7);
    // JIT load this step's K/V (issued before the barrier so the HBM
    // latency overlaps the barrier wait; regs are short-lived)
    int4 kr[2], vr[2];
#pragma unroll
    for (int i = 0; i < 2; i++) {
      kr[i] = *(const int4*)(kh + ((hbase + tb + k0 + krow[i]) << 6) + kc * 8);
      vr[i] = *(const int4*)(vT + (((size_t)h * 64 + vf[i]) << 12) + tb + k0 + vc * 8);
    }
    __syncthreads();                 // prev-step LDS consumers done
#pragma unroll
    for (int i = 0; i < 2; i++) {
      *(int4*)&kS[krow[i] * 72 + kc * 8] = kr[i];
      union { int4 v; s16x4 hh[2]; } tv; tv.v = vr[i];
      *(s16x4*)&vS[vf[i] * 136 + vc0] = tv.hh[0];
      *(s16x4*)&vS[vf[i] * 136 + vc1] = tv.hh[1];
    }
    __syncthreads();

    // two 64-token halves: sc[4] live instead of sc[8]
#pragma unroll
    for (int hs = 0; hs < 2; hs++) {
      const int kbase = k0 + hs * 64;
      f32x4 sc[4];
#pragma unroll
      for (int kt4 = 0; kt4 < 4; kt4++) {
        const int kt = hs * 4 + kt4;
        const u16* kp = &kS[(kt * 16 + m) * 72 + quad * 8];
        bf16x8 ka0 = *(const bf16x8*)kp;
        bf16x8 ka1 = *(const bf16x8*)(kp + 32);
        f32x4 t = zero4;
        t = __builtin_amdgcn_mfma_f32_16x16x32_bf16(ka0, qb0, t, 0, 0, 0);
        t = __builtin_amdgcn_mfma_f32_16x16x32_bf16(ka1, qb1, t, 0, 0, 0);
        sc[kt4] = t;
      }
      if (kbase + 64 > q0) {   // touches diagonal region: causal mask
#pragma unroll
        for (int kt4 = 0; kt4 < 4; kt4++)
#pragma unroll
          for (int r = 0; r < 4; r++) {
            int ktok = kbase + kt4 * 16 + quad * 4 + r;
            if (ktok > qg) sc[kt4][r] = -30000.f;
          }
      }
      // per-lane max over 16 regs + 2 shuffles (q fixed per lane)
      float mx = sc[0][0];
#pragma unroll
      for (int kt4 = 0; kt4 < 4; kt4++)
#pragma unroll
        for (int r = 0; r < 4; r++) mx = fmaxf(mx, sc[kt4][r]);
      mx = fmaxf(mx, __shfl_xor(mx, 16, 64));
      mx = fmaxf(mx, __shfl_xor(mx, 32, 64));
      // defer-max (T13): only rescale when max grew by > 8 (exp2 domain)
      if (!__all(mx <= mrow + 8.f)) {
        float mnew = fmaxf(mrow, mx);
        float alpha = __builtin_amdgcn_exp2f(mrow - mnew);
        lrow *= alpha;
#pragma unroll
        for (int ft = 0; ft < 4; ft++) O[ft] *= alpha;
        mrow = mnew;
      }
      // P^T = exp2(S^T - m): pack to bf16 B-frags; accumulate l inline
      s16x4 pb[4];
      float sum = 0.f;
#pragma unroll
      for (int kt4 = 0; kt4 < 4; kt4++) {
        float e0 = __builtin_amdgcn_exp2f(sc[kt4][0] - mrow);
        float e1 = __builtin_amdgcn_exp2f(sc[kt4][1] - mrow);
        float e2 = __builtin_amdgcn_exp2f(sc[kt4][2] - mrow);
        float e3 = __builtin_amdgcn_exp2f(sc[kt4][3] - mrow);
        sum += (e0 + e1) + (e2 + e3);
        union { uint2 u; s16x4 hh; } pu;
        pu.u.x = pkbf(e0, e1);
        pu.u.y = pkbf(e2, e3);
        pb[kt4] = pu.hh;
      }
      sum += __shfl_xor(sum, 16, 64);
      sum += __shfl_xor(sum, 32, 64);
      lrow += sum;
      // O^T += V^T·P^T via 16x16x16 over this half's k-slots
      // (pr = hs*2 + p2; 8 contiguous u16 = 2 A-frags per b128 read)
#pragma unroll
      for (int ft = 0; ft < 4; ft++) {
        const u16* vp = &vS[(ft * 16 + m) * 136 + quad * 32 + hs * 16];
#pragma unroll
        for (int p2 = 0; p2 < 2; p2++) {
          union { bf16x8 v; s16x4 hh[2]; } u;
          u.v = *(const bf16x8*)(vp + p2 * 8);
          O[ft] = mfma16(u.hh[0], pb[2 * p2],     O[ft]);
          O[ft] = mfma16(u.hh[1], pb[2 * p2 + 1], O[ft]);
        }
      }
    }
  }

  // nc==1: normalize in-kernel (diagonal guarantees lrow > 0)
  if (nc == 1) {
    float inv = 1.f / lrow;
#pragma unroll
    for (int ft = 0; ft < 4; ft++) O[ft] *= inv;
  }

  // O^T -> LDS bounce (kS reused, 128 rows x 64f) -> coalesced global stores
  __syncthreads();
#pragma unroll
  for (int ft = 0; ft < 4; ft++) {
    union { uint2 u; s16x4 hh; } o4;
    o4.u.x = pkbf(O[ft][0], O[ft][1]);
    o4.u.y = pkbf(O[ft][2], O[ft][3]);
    *(s16x4*)&kS[(w * 16 + m) * 72 + ft * 16 + quad * 4] = o4.hh;
  }
  __syncthreads();
  if (nc == 1) {
    // direct z write: [tok][1024] layout, this head's 64-col stripe
    u16* zp = z + ((tb + (size_t)q0) << 10) + h * 64;
#pragma unroll
    for (int it = 0; it < 2; it++) {
      int idx = it * 512 + tid;
      int row = idx >> 3, c = idx & 7;
      *(int4*)&zp[((size_t)row << 10) + c * 8] = *(const int4*)&kS[row * 72 + c * 8];
    }
  } else {
    const int slot = (combo * 16 + qt) * 2 + ci;
    u16* op = Opart + ((size_t)slot << 13);
#pragma unroll
    for (int it = 0; it < 2; it++) {
      int idx = it * 512 + tid;
      int row = idx >> 3, c = idx & 7;
      *(int4*)&op[row * 64 + c * 8] = *(const int4*)&kS[row * 72 + c * 8];
    }
    if (quad == 0) {
      stats[slot * 256 + w * 16 + m]       = mrow;
      stats[slot * 256 + 128 + w * 16 + m] = lrow;
    }
  }
}

// merge partials -> z [t][1024]; only qt>=8 tiles (nc==2) reach here. 512 thr.
__global__ __launch_bounds__(512) void attn_merge(
    const u16* __restrict__ Opart, const float* __restrict__ stats,
    u16* __restrict__ z) {
  const int combo = blockIdx.x, qt = 8 + blockIdx.y;
  const int h = combo >> 1, b = combo & 1;
  const int q0 = qt << 7;
  const int tid = threadIdx.x;
  const int t = tid >> 2, f0 = (tid & 3) << 4;   // t 0..127
  const int slot0 = (combo * 16 + qt) * 2;
  float M = fmaxf(stats[slot0 * 256 + t], stats[(slot0 + 1) * 256 + t]);
  float acc[16];
#pragma unroll
  for (int e = 0; e < 16; e++) acc[e] = 0.f;
  float ltot = 0.f;
#pragma unroll
  for (int ci = 0; ci < 2; ci++) {
    float mi = stats[(slot0 + ci) * 256 + t];
    float li = stats[(slot0 + ci) * 256 + 128 + t];
    float wgt = exp2f(mi - M);
    ltot += wgt * li;
    const u16* op = Opart + (((size_t)(slot0 + ci)) << 13) + t * 64 + f0;
    union { int4 v; u16 u[8]; } a0, a1;
    a0.v = *(const int4*)op;
    a1.v = *(const int4*)(op + 8);
#pragma unroll
    for (int e = 0; e < 8; e++) {
      acc[e]     += wgt * bf2f(a0.u[e]);
      acc[8 + e] += wgt * bf2f(a1.u[e]);
    }
  }
  float inv = 1.f / ltot;
  union { int4 v; u16 u[8]; } o0, o1;
#pragma unroll
  for (int e = 0; e < 8; e++) {
    o0.u[e] = f2bf(acc[e] * inv);
    o1.u[e] = f2bf(acc[8 + e] * inv);
  }
  size_t tok = (size_t)b * 2048 + q0 + t;
  *(int4*)&z[tok * 1024 + h * 64 + f0]     = o0.v;
  *(int4*)&z[tok * 1024 + h * 64 + f0 + 8] = o1.v;
}

// ---------------------------------------------------------------------------
extern "C" void kernel_launch(void* const* d_in, const int* in_sizes, int n_in,
                              void* d_out, int out_size, void* d_ws, size_t ws_size,
                              hipStream_t stream) {
  (void)in_sizes; (void)n_in; (void)out_size; (void)ws_size;
  const void* resid_pre = d_in[0];
  const void* ln1_w = d_in[1];
  const void* ln1_b = d_in[2];
  const void* W_Q   = d_in[3];
  const void* b_Q   = d_in[4];
  const void* W_K   = d_in[5];
  const void* b_K   = d_in[6];
  const void* W_V   = d_in[7];
  const void* b_V   = d_in[8];
  const void* W_O   = d_in[9];
  const void* b_O   = d_in[10];
  const void* ln2_w = d_in[11];
  const void* ln2_b = d_in[12];
  const void* W_in  = d_in[13];
  const void* b_in  = d_in[14];
  const void* W_out = d_in[15];
  const void* b_out = d_in[16];

  char* p = (char*)d_ws;
  auto alloc = [&](size_t bytes) {
    char* r = p; p += (bytes + 255) & ~(size_t)255; return (void*)r;
  };
  int*   flag      = (int*)  alloc(256);
  u16*   WqkvT     = (u16*)  alloc(3072ull * 1024 * 2);
  u16*   WoT       = (u16*)  alloc(1024ull * 1024 * 2);
  u16*   WinT      = (u16*)  alloc(4096ull * 1024 * 2);
  u16*   WoutT     = (u16*)  alloc(1024ull * 4096 * 2);
  float* biases    = (float*)alloc(9216 * 4);
  u16*   xn        = (u16*)  alloc(4096ull * 1024 * 2);  // reused as z
  u16*   q_hm      = (u16*)  alloc(16ull * 4096 * 64 * 2);
  u16*   k_hm      = (u16*)  alloc(16ull * 4096 * 64 * 2);
  u16*   vTws      = (u16*)  alloc(16ull * 64 * 4096 * 2);
  float* resid_mid = (float*)alloc(4096ull * 1024 * 4);
  u16*   h2        = (u16*)  alloc(4096ull * 1024 * 2);  // attn stats before ln2
  u16*   act       = (u16*)  alloc(4096ull * 4096 * 2);  // attn partials before MLP
  u16*   z = xn;
  u16*   Opart = act;              // 1024 slots x 16 KB = 16 MB (< 32 MB)
  float* stats = (float*)h2;       // 1024 slots x 256 fp32 = 1 MB < 8 MB

  detect_dtype<<<1, 256, 0, stream>>>((const unsigned int*)resid_pre, flag);

  pack_qkv_tiled<<<dim3(16, 48), 256, 0, stream>>>(flag, W_Q, W_K, W_V, WqkvT);
  transpose_tiled<<<dim3(16, 16), 256, 0, stream>>>(flag, W_O,   WoT,   1024, 1024);
  transpose_tiled<<<dim3(64, 16), 256, 0, stream>>>(flag, W_in,  WinT,  1024, 4096);
  transpose_tiled<<<dim3(16, 64), 256, 0, stream>>>(flag, W_out, WoutT, 4096, 1024);
  pack_biases<<<36, 256, 0, stream>>>(flag, b_Q, b_K, b_V, b_O, b_in, b_out, biases);

  ln_fwd<0><<<4096, 256, 0, stream>>>(flag, resid_pre, ln1_w, ln1_b, xn);
  // qkv -> head-major q/k + transposed v. grid: 8 XCD x SH=4 rows x 24 cols
  gemm_bt<4, 128, 1><<<768, 256, 0, stream>>>(
      flag, xn, WqkvT, biases, nullptr, q_hm, k_hm, vTws, 4096, 3072, 1024, 2);
  // split-K causal flash attention (128-q tiles, 1024-chunks) -> z
  attn_part<<<dim3(32, 16, 2), 512, 0, stream>>>(q_hm, k_hm, vTws, Opart, stats, z);
  attn_merge<<<dim3(32, 8), 512, 0, stream>>>(Opart, stats, z);
  // resid_mid = resid_pre + z @ W_O + b_O   (fp32). 8 XCD x SH=8 x 8 cols,
  // in-block split-K (512 thr)
  gemm_bt<2, 64, 2><<<512, 512, 0, stream>>>(
      flag, z, WoT, biases + 3072, resid_pre, resid_mid, nullptr, nullptr, 4096, 1024, 1024, 3);
  ln_fwd<1><<<4096, 256, 0, stream>>>(flag, resid_mid, ln2_w, ln2_b, h2);
  // act = relu(h2 @ W_in + b_in). 8 XCD x SH=4 x 32 cols
  gemm_bt<1, 128, 1><<<1024, 256, 0, stream>>>(
      flag, h2, WinT, biases + 4096, nullptr, act, nullptr, nullptr, 4096, 4096, 1024, 2);
  // out = resid_mid + act @ W_out + b_out. 8 XCD x SH=8 x 8 cols,
  // in-block split-K (512 thr)
  gemm_bt<3, 64, 2><<<512, 512, 0, stream>>>(
      flag, act, WoutT, biases + 8192, resid_mid, d_out, nullptr, nullptr, 4096, 1024, 4096, 3);
}